// Round 1
// baseline (660.398 us; speedup 1.0000x reference)
//
#include <hip/hip_runtime.h>
#include <math.h>

#define NN 50000
#define EE 1600000
#define DD 128

// workspace layout (bytes)
#define HV_OFF      0            // [NN*128] f32 = 25,600,000
#define LD_OFF      25600000     // [NN] f32
#define LS_OFF      25800000     // [NN] f32
#define START_OFF   26000000     // [NN] i32
#define CUR_OFF     26200000     // [NN] i32
#define EID_OFF     26400000     // [EE] i32 = 6,400,000
#define COUNT_OFF   32800000     // [NN] i32   (zeroed)
#define CURSOR_OFF  33000000     // 1 i32 (pad 256, zeroed)
#define BSUM_OFF    33000256     // [128] f32 (zeroed)
#define BSQ_OFF     33000768     // [128] f32 (zeroed)
#define MEAN_OFF    33001280     // [128] f32
#define ISTD_OFF    33001792     // [128] f32
#define ZERO_LEN    201280       // count + cursor pad + bsum + bsq

// ---------------------------------------------------------------- per-node dots
__global__ __launch_bounds__(256) void k_dots(const float* __restrict__ nf,
    const float* __restrict__ wd, const float* __restrict__ wsrc,
    float* __restrict__ ld, float* __restrict__ ls) {
  int wid = (blockIdx.x * 256 + threadIdx.x) >> 6;
  int lane = threadIdx.x & 63;
  if (wid >= NN) return;
  float2 x = ((const float2*)(nf + (size_t)wid * DD))[lane];
  float2 a = ((const float2*)wd)[lane];
  float2 b = ((const float2*)wsrc)[lane];
  float pa = x.x * a.x + x.y * a.y;
  float pb = x.x * b.x + x.y * b.y;
  #pragma unroll
  for (int o = 32; o; o >>= 1) { pa += __shfl_xor(pa, o); pb += __shfl_xor(pb, o); }
  if (lane == 0) { ld[wid] = pa; ls[wid] = pb; }
}

// ---------------------------------------------------------------- hv = nf @ w_proj + b_proj
#define HV_NPB 8
__global__ __launch_bounds__(128) void k_hv(const float* __restrict__ nf,
    const float* __restrict__ wp, const float* __restrict__ bp,
    float* __restrict__ hv) {
  __shared__ float xs[HV_NPB][132];
  int t = threadIdx.x;                // output feature
  int base = blockIdx.x * HV_NPB;
  #pragma unroll
  for (int i = 0; i < HV_NPB; ++i) xs[i][t] = nf[(size_t)(base + i) * DD + t];
  __syncthreads();
  float bb = bp[t];
  float acc[HV_NPB];
  #pragma unroll
  for (int i = 0; i < HV_NPB; ++i) acc[i] = bb;
  for (int k4 = 0; k4 < DD / 4; ++k4) {
    float w0 = wp[(size_t)(4 * k4 + 0) * DD + t];
    float w1_ = wp[(size_t)(4 * k4 + 1) * DD + t];
    float w2_ = wp[(size_t)(4 * k4 + 2) * DD + t];
    float w3_ = wp[(size_t)(4 * k4 + 3) * DD + t];
    #pragma unroll
    for (int i = 0; i < HV_NPB; ++i) {
      float4 xv = *(const float4*)&xs[i][4 * k4];
      acc[i] += xv.x * w0 + xv.y * w1_ + xv.z * w2_ + xv.w * w3_;
    }
  }
  #pragma unroll
  for (int i = 0; i < HV_NPB; ++i) hv[(size_t)(base + i) * DD + t] = acc[i];
}

// ---------------------------------------------------------------- CSR build
__global__ __launch_bounds__(256) void k_count(const int* __restrict__ dst,
                                               int* __restrict__ count) {
  int e = blockIdx.x * 256 + threadIdx.x;
  if (e < EE) atomicAdd(&count[dst[e]], 1);
}

__global__ __launch_bounds__(256) void k_offsets(const int* __restrict__ count,
    int* __restrict__ start, int* __restrict__ cur, int* __restrict__ cursor) {
  int n = blockIdx.x * 256 + threadIdx.x;
  if (n < NN) {
    int c = count[n];
    int s = atomicAdd(cursor, c);
    start[n] = s;
    cur[n] = s;
  }
}

__global__ __launch_bounds__(256) void k_fill(const int* __restrict__ dst,
    int* __restrict__ cur, int* __restrict__ eid) {
  int e = blockIdx.x * 256 + threadIdx.x;
  if (e < EE) {
    int p = atomicAdd(&cur[dst[e]], 1);
    eid[p] = e;
  }
}

// ---------------------------------------------------------------- edge softmax + aggregate + ELU
__global__ __launch_bounds__(256) void k_agg(const float* __restrict__ hv,
    const float* __restrict__ ld, const float* __restrict__ ls,
    const int* __restrict__ srcv, const float* __restrict__ be_p,
    const int* __restrict__ start, const int* __restrict__ count,
    const int* __restrict__ eid, float* __restrict__ context) {
  int wid = (blockIdx.x * 256 + threadIdx.x) >> 6;   // one wave per node
  int lane = threadIdx.x & 63;
  if (wid >= NN) return;
  int cnt = count[wid];
  float2 acc = make_float2(0.f, 0.f);
  float2* outp = (float2*)(context + (size_t)wid * DD);
  if (cnt == 0) { outp[lane] = acc; return; }
  int s = start[wid];
  float base = ld[wid] + be_p[0];
  float m = -INFINITY;
  float dsum = 0.f;   // per-lane partial
  for (int c0 = 0; c0 < cnt; c0 += 64) {
    int len = min(64, cnt - c0);
    float lg = -INFINITY;
    int sv = 0;
    if (lane < len) {
      int e = eid[s + c0 + lane];
      sv = srcv[e];
      float l = base + ls[sv];
      lg = (l >= 0.f) ? l : 0.01f * l;
    }
    float cm = lg;
    #pragma unroll
    for (int o = 32; o; o >>= 1) cm = fmaxf(cm, __shfl_xor(cm, o));
    float nm = fmaxf(m, cm);
    float scale = expf(m - nm);            // first chunk: exp(-inf)=0
    acc.x *= scale; acc.y *= scale; dsum *= scale;
    float ev = (lane < len) ? expf(lg - nm) : 0.f;
    dsum += ev;
    for (int j = 0; j < len; ++j) {
      float evj = __shfl(ev, j);
      int svj = __shfl(sv, j);
      float2 hvv = ((const float2*)(hv + (size_t)svj * DD))[lane];
      acc.x += evj * hvv.x;
      acc.y += evj * hvv.y;
    }
    m = nm;
  }
  #pragma unroll
  for (int o = 32; o; o >>= 1) dsum += __shfl_xor(dsum, o);
  float r = 1.f / dsum;
  float cx = acc.x * r, cy = acc.y * r;
  cx = (cx > 0.f) ? cx : expm1f(cx);       // ELU
  cy = (cy > 0.f) ? cy : expm1f(cy);
  outp[lane] = make_float2(cx, cy);
}

// ---------------------------------------------------------------- MLP (+BN partial stats)
// ctx aliases out: each block reads its own rows before overwriting them.
#define MNPB 16
__global__ __launch_bounds__(128) void k_mlp(const float* ctx, const float* __restrict__ nf,
    const float* __restrict__ w1, const float* __restrict__ b1,
    const float* __restrict__ w2, const float* __restrict__ b2,
    float* out, float* __restrict__ bn_sum, float* __restrict__ bn_sumsq) {
  __shared__ float xs[MNPB][260];
  int t = threadIdx.x;                 // output feature
  int base = blockIdx.x * MNPB;
  #pragma unroll
  for (int i = 0; i < MNPB; ++i) {
    xs[i][t] = ctx[(size_t)(base + i) * DD + t];
    xs[i][DD + t] = nf[(size_t)(base + i) * DD + t];
  }
  __syncthreads();
  float acc[MNPB];
  float bb = b1[t];
  #pragma unroll
  for (int i = 0; i < MNPB; ++i) acc[i] = bb;
  for (int k4 = 0; k4 < (2 * DD) / 4; ++k4) {
    float w0 = w1[(size_t)(4 * k4 + 0) * DD + t];
    float wa = w1[(size_t)(4 * k4 + 1) * DD + t];
    float wb = w1[(size_t)(4 * k4 + 2) * DD + t];
    float wc = w1[(size_t)(4 * k4 + 3) * DD + t];
    #pragma unroll
    for (int i = 0; i < MNPB; ++i) {
      float4 xv = *(const float4*)&xs[i][4 * k4];
      acc[i] += xv.x * w0 + xv.y * wa + xv.z * wb + xv.w * wc;
    }
  }
  float h1v[MNPB];
  #pragma unroll
  for (int i = 0; i < MNPB; ++i) h1v[i] = fmaxf(acc[i], 0.f);
  __syncthreads();
  #pragma unroll
  for (int i = 0; i < MNPB; ++i) xs[i][t] = h1v[i];
  __syncthreads();
  float bb2 = b2[t];
  #pragma unroll
  for (int i = 0; i < MNPB; ++i) acc[i] = bb2;
  for (int k4 = 0; k4 < DD / 4; ++k4) {
    float w0 = w2[(size_t)(4 * k4 + 0) * DD + t];
    float wa = w2[(size_t)(4 * k4 + 1) * DD + t];
    float wb = w2[(size_t)(4 * k4 + 2) * DD + t];
    float wc = w2[(size_t)(4 * k4 + 3) * DD + t];
    #pragma unroll
    for (int i = 0; i < MNPB; ++i) {
      float4 xv = *(const float4*)&xs[i][4 * k4];
      acc[i] += xv.x * w0 + xv.y * wa + xv.z * wb + xv.w * wc;
    }
  }
  float lsum = 0.f, lsq = 0.f;
  #pragma unroll
  for (int i = 0; i < MNPB; ++i) {
    float h = fmaxf(acc[i], 0.f);
    out[(size_t)(base + i) * DD + t] = h;
    lsum += h;
    lsq += h * h;
  }
  atomicAdd(&bn_sum[t], lsum);
  atomicAdd(&bn_sumsq[t], lsq);
}

// ---------------------------------------------------------------- BN stats + normalize
__global__ __launch_bounds__(128) void k_bnstats(const float* __restrict__ bn_sum,
    const float* __restrict__ bn_sumsq, float* __restrict__ mean,
    float* __restrict__ istd) {
  int t = threadIdx.x;
  float mu = bn_sum[t] / (float)NN;
  float var = bn_sumsq[t] / (float)NN - mu * mu;
  var = fmaxf(var, 0.f);
  mean[t] = mu;
  istd[t] = 1.f / sqrtf(var + 1e-5f);
}

__global__ __launch_bounds__(256) void k_bnorm(float* __restrict__ out,
    const float* __restrict__ mean, const float* __restrict__ istd,
    const float* __restrict__ gamma, const float* __restrict__ beta) {
  int idx = blockIdx.x * 256 + threadIdx.x;   // float4 index, exact cover
  float4* p = (float4*)out;
  float4 v = p[idx];
  int f = (idx & 31) << 2;
  v.x = gamma[f + 0] * (v.x - mean[f + 0]) * istd[f + 0] + beta[f + 0];
  v.y = gamma[f + 1] * (v.y - mean[f + 1]) * istd[f + 1] + beta[f + 1];
  v.z = gamma[f + 2] * (v.z - mean[f + 2]) * istd[f + 2] + beta[f + 2];
  v.w = gamma[f + 3] * (v.w - mean[f + 3]) * istd[f + 3] + beta[f + 3];
  p[idx] = v;
}

// ----------------------------------------------------------------
extern "C" void kernel_launch(void* const* d_in, const int* in_sizes, int n_in,
                              void* d_out, int out_size, void* d_ws, size_t ws_size,
                              hipStream_t stream) {
  (void)in_sizes; (void)n_in; (void)out_size; (void)ws_size;
  const float* nf    = (const float*)d_in[0];
  const int*   src   = (const int*)d_in[1];
  const int*   dst   = (const int*)d_in[2];
  const float* wed   = (const float*)d_in[3];
  const float* wes   = (const float*)d_in[4];
  const float* be    = (const float*)d_in[5];
  const float* wp    = (const float*)d_in[6];
  const float* bp    = (const float*)d_in[7];
  const float* w1    = (const float*)d_in[8];
  const float* b1    = (const float*)d_in[9];
  const float* w2    = (const float*)d_in[10];
  const float* b2    = (const float*)d_in[11];
  const float* gamma = (const float*)d_in[12];
  const float* beta  = (const float*)d_in[13];
  float* out = (float*)d_out;
  char* ws = (char*)d_ws;

  float* hv    = (float*)(ws + HV_OFF);
  float* ld    = (float*)(ws + LD_OFF);
  float* ls    = (float*)(ws + LS_OFF);
  int*   start = (int*)(ws + START_OFF);
  int*   cur   = (int*)(ws + CUR_OFF);
  int*   eid   = (int*)(ws + EID_OFF);
  int*   count = (int*)(ws + COUNT_OFF);
  int*   cursor= (int*)(ws + CURSOR_OFF);
  float* bsum  = (float*)(ws + BSUM_OFF);
  float* bsq   = (float*)(ws + BSQ_OFF);
  float* mean  = (float*)(ws + MEAN_OFF);
  float* istd  = (float*)(ws + ISTD_OFF);

  hipMemsetAsync(ws + COUNT_OFF, 0, ZERO_LEN, stream);

  k_dots<<<12500, 256, 0, stream>>>(nf, wed, wes, ld, ls);
  k_hv<<<NN / HV_NPB, 128, 0, stream>>>(nf, wp, bp, hv);
  k_count<<<EE / 256, 256, 0, stream>>>(dst, count);
  k_offsets<<<(NN + 255) / 256, 256, 0, stream>>>(count, start, cur, cursor);
  k_fill<<<EE / 256, 256, 0, stream>>>(dst, cur, eid);
  k_agg<<<12500, 256, 0, stream>>>(hv, ld, ls, src, be, start, count, eid, out);
  k_mlp<<<NN / MNPB, 128, 0, stream>>>(out, nf, w1, b1, w2, b2, out, bsum, bsq);
  k_bnstats<<<1, 128, 0, stream>>>(bsum, bsq, mean, istd);
  k_bnorm<<<(NN * DD / 4) / 256, 256, 0, stream>>>(out, mean, istd, gamma, beta);
}

// Round 2
// 518.583 us; speedup vs baseline: 1.2735x; 1.2735x over previous
//
#include <hip/hip_runtime.h>
#include <math.h>

#define NN 50000
#define EE 1600000
#define DD 128

typedef __attribute__((ext_vector_type(8))) short short8v;
typedef __attribute__((ext_vector_type(4))) float f32x4;

// workspace layout (bytes)
#define HVB_OFF     0            // [NN*128] bf16 = 12,800,000
#define NFB_OFF     12800000     // [NN*128] bf16 = 12,800,000
#define LD_OFF      25600000     // [NN] f32
#define LS_OFF      25800000     // [NN] f32
#define START_OFF   26000000     // [NN] i32
#define CUR_OFF     26200000     // [NN] i32
#define EID_OFF     26400000     // [EE] i32 = 6,400,000
#define W1T_OFF     32800000     // [128*256] bf16 = 65,536
#define W2T_OFF     32865536     // [128*128] bf16 = 32,768
#define WPT_OFF     32898304     // [128*128] bf16 = 32,768
#define COUNT_OFF   32931072     // [NN] i32   (zeroed)
#define CURSOR_OFF  33131072     // 1 i32 (pad 256, zeroed)
#define BSUM_OFF    33131328     // [128] f32 (zeroed)
#define BSQ_OFF     33131840     // [128] f32 (zeroed)
#define MEAN_OFF    33132352     // [128] f32
#define ISTD_OFF    33132864     // [128] f32
#define ZERO_LEN    201280       // count + cursor pad + bsum + bsq

__device__ __forceinline__ unsigned short f2bf(float f) {
  union { float f; unsigned u; } v; v.f = f;
  unsigned r = v.u + 0x7FFFu + ((v.u >> 16) & 1u);   // round-to-nearest-even
  return (unsigned short)(r >> 16);
}

// ---------------------------------------------------------------- prep: nf -> bf16
__global__ __launch_bounds__(256) void k_cast_nf(const float* __restrict__ nf,
                                                 unsigned short* __restrict__ nfb) {
  int i = blockIdx.x * 256 + threadIdx.x;            // float4 index, exact cover
  float4 v = *(const float4*)(nf + (size_t)i * 4);
  ushort4 b;
  b.x = f2bf(v.x); b.y = f2bf(v.y); b.z = f2bf(v.z); b.w = f2bf(v.w);
  *(ushort4*)(nfb + (size_t)i * 4) = b;
}

// ---------------------------------------------------------------- prep: weight transposes (to [n][k] bf16)
__global__ __launch_bounds__(256) void k_prep_w(const float* __restrict__ w1,
    const float* __restrict__ w2, const float* __restrict__ wp,
    unsigned short* __restrict__ w1t, unsigned short* __restrict__ w2t,
    unsigned short* __restrict__ wpt) {
  int t = blockIdx.x * 256 + threadIdx.x;            // 0..65535
  if (t < 32768) {
    int n = t & 127, k = t >> 7;                     // k 0..255
    w1t[n * 256 + k] = f2bf(w1[(size_t)k * 128 + n]);
  } else if (t < 49152) {
    int i = t - 32768; int n = i & 127, k = i >> 7;
    w2t[n * 128 + k] = f2bf(w2[(size_t)k * 128 + n]);
  } else {
    int i = t - 49152; int n = i & 127, k = i >> 7;
    wpt[n * 128 + k] = f2bf(wp[(size_t)k * 128 + n]);
  }
}

// ---------------------------------------------------------------- per-node dots
__global__ __launch_bounds__(256) void k_dots(const float* __restrict__ nf,
    const float* __restrict__ wd, const float* __restrict__ wsrc,
    float* __restrict__ ld, float* __restrict__ ls) {
  int wid = (blockIdx.x * 256 + threadIdx.x) >> 6;
  int lane = threadIdx.x & 63;
  if (wid >= NN) return;
  float2 x = ((const float2*)(nf + (size_t)wid * DD))[lane];
  float2 a = ((const float2*)wd)[lane];
  float2 b = ((const float2*)wsrc)[lane];
  float pa = x.x * a.x + x.y * a.y;
  float pb = x.x * b.x + x.y * b.y;
  #pragma unroll
  for (int o = 32; o; o >>= 1) { pa += __shfl_xor(pa, o); pb += __shfl_xor(pb, o); }
  if (lane == 0) { ld[wid] = pa; ls[wid] = pb; }
}

// ---------------------------------------------------------------- hv = bf16( nf @ w_proj + b_proj )  [MFMA]
__global__ __launch_bounds__(256) void k_hv2(const unsigned short* __restrict__ nfb,
    const unsigned short* __restrict__ wpt, const float* __restrict__ bp,
    unsigned short* __restrict__ hvb) {
  __shared__ unsigned short xs[64][136];             // pad: row stride 272 B (4-bank rotate)
  int tid = threadIdx.x;
  int m0 = blockIdx.x * 64;
  #pragma unroll
  for (int e = 0; e < 4; ++e) {
    int idx = tid + 256 * e;                         // uint4 index, 1024 total
    int row = idx >> 4, c8 = idx & 15;
    int m = m0 + row; if (m >= NN) m = NN - 1;
    uint4 v = *(const uint4*)(nfb + (size_t)m * 128 + c8 * 8);
    *(uint4*)&xs[row][c8 * 8] = v;
  }
  __syncthreads();
  int wid = tid >> 6, lane = tid & 63;
  int wm = wid >> 1, wn = wid & 1;
  int l15 = lane & 15, lg = lane >> 4;
  f32x4 acc[2][4];
  #pragma unroll
  for (int mf = 0; mf < 2; ++mf)
    #pragma unroll
    for (int nf = 0; nf < 4; ++nf) acc[mf][nf] = (f32x4){0.f, 0.f, 0.f, 0.f};
  for (int ks = 0; ks < 4; ++ks) {
    short8v a[2], b[4];
    #pragma unroll
    for (int mf = 0; mf < 2; ++mf)
      a[mf] = *(const short8v*)&xs[wm * 32 + mf * 16 + l15][ks * 32 + lg * 8];
    #pragma unroll
    for (int nf = 0; nf < 4; ++nf) {
      int n = wn * 64 + nf * 16 + l15;
      b[nf] = *(const short8v*)(wpt + (size_t)n * 128 + ks * 32 + lg * 8);
    }
    #pragma unroll
    for (int mf = 0; mf < 2; ++mf)
      #pragma unroll
      for (int nf = 0; nf < 4; ++nf)
        acc[mf][nf] = __builtin_amdgcn_mfma_f32_16x16x32_bf16(a[mf], b[nf], acc[mf][nf], 0, 0, 0);
  }
  float bpn[4];
  #pragma unroll
  for (int nf = 0; nf < 4; ++nf) bpn[nf] = bp[wn * 64 + nf * 16 + l15];
  #pragma unroll
  for (int mf = 0; mf < 2; ++mf)
    #pragma unroll
    for (int nf = 0; nf < 4; ++nf)
      #pragma unroll
      for (int r = 0; r < 4; ++r) {
        int m = m0 + wm * 32 + mf * 16 + lg * 4 + r;
        int n = wn * 64 + nf * 16 + l15;
        if (m < NN) hvb[(size_t)m * 128 + n] = f2bf(acc[mf][nf][r] + bpn[nf]);
      }
}

// ---------------------------------------------------------------- CSR build
__global__ __launch_bounds__(256) void k_count(const int* __restrict__ dst,
                                               int* __restrict__ count) {
  int e = blockIdx.x * 256 + threadIdx.x;
  if (e < EE) atomicAdd(&count[dst[e]], 1);
}

__global__ __launch_bounds__(256) void k_offsets(const int* __restrict__ count,
    int* __restrict__ start, int* __restrict__ cur, int* __restrict__ cursor) {
  int n = blockIdx.x * 256 + threadIdx.x;
  if (n < NN) {
    int c = count[n];
    int s = atomicAdd(cursor, c);
    start[n] = s;
    cur[n] = s;
  }
}

__global__ __launch_bounds__(256) void k_fill(const int* __restrict__ dst,
    int* __restrict__ cur, int* __restrict__ eid) {
  int e = blockIdx.x * 256 + threadIdx.x;
  if (e < EE) {
    int p = atomicAdd(&cur[dst[e]], 1);
    eid[p] = e;
  }
}

// ---------------------------------------------------------------- edge softmax + aggregate + ELU
__global__ __launch_bounds__(256) void k_agg(const unsigned short* __restrict__ hvb,
    const float* __restrict__ ld, const float* __restrict__ ls,
    const int* __restrict__ srcv, const float* __restrict__ be_p,
    const int* __restrict__ start, const int* __restrict__ count,
    const int* __restrict__ eid, float* __restrict__ context) {
  int wid = (blockIdx.x * 256 + threadIdx.x) >> 6;   // one wave per node
  int lane = threadIdx.x & 63;
  if (wid >= NN) return;
  int cnt = count[wid];
  float2 acc = make_float2(0.f, 0.f);
  float2* outp = (float2*)(context + (size_t)wid * DD);
  if (cnt == 0) { outp[lane] = acc; return; }
  int s = start[wid];
  float base = ld[wid] + be_p[0];
  float m = -INFINITY;
  float dsum = 0.f;
  for (int c0 = 0; c0 < cnt; c0 += 64) {
    int len = min(64, cnt - c0);
    float lg = -INFINITY;
    int sv = 0;
    if (lane < len) {
      int e = eid[s + c0 + lane];
      sv = srcv[e];
      float l = base + ls[sv];
      lg = (l >= 0.f) ? l : 0.01f * l;
    }
    float cm = lg;
    #pragma unroll
    for (int o = 32; o; o >>= 1) cm = fmaxf(cm, __shfl_xor(cm, o));
    float nm = fmaxf(m, cm);
    float scale = expf(m - nm);
    acc.x *= scale; acc.y *= scale; dsum *= scale;
    float ev = (lane < len) ? expf(lg - nm) : 0.f;
    dsum += ev;
    for (int j = 0; j < len; ++j) {
      float evj = __shfl(ev, j);
      int svj = __shfl(sv, j);
      unsigned u = ((const unsigned*)(hvb + (size_t)svj * DD))[lane];  // 2 bf16
      union { unsigned u; float f; } vl, vh;
      vl.u = u << 16;
      vh.u = u & 0xFFFF0000u;
      acc.x += evj * vl.f;
      acc.y += evj * vh.f;
    }
    m = nm;
  }
  #pragma unroll
  for (int o = 32; o; o >>= 1) dsum += __shfl_xor(dsum, o);
  float r = 1.f / dsum;
  float cx = acc.x * r, cy = acc.y * r;
  cx = (cx > 0.f) ? cx : expm1f(cx);
  cy = (cy > 0.f) ? cy : expm1f(cy);
  outp[lane] = make_float2(cx, cy);
}

// ---------------------------------------------------------------- fused MLP [MFMA] + BN partials
// ctx aliases out: each block reads only its own rows (before overwriting them in epilogue).
__global__ __launch_bounds__(256) void k_mlp2(const float* ctx,
    const unsigned short* __restrict__ nfb,
    const unsigned short* __restrict__ w1t, const float* __restrict__ b1,
    const unsigned short* __restrict__ w2t, const float* __restrict__ b2,
    float* out, float* __restrict__ bn_sum, float* __restrict__ bn_sumsq) {
  __shared__ unsigned short xs[64][264];             // [row][k] bf16, row stride 528 B
  __shared__ unsigned short h1s[64][136];            // row stride 272 B
  __shared__ float bns[128], bnq[128];
  int tid = threadIdx.x;
  int m0 = blockIdx.x * 64;
  if (tid < 128) { bns[tid] = 0.f; bnq[tid] = 0.f; }
  // stage ctx -> xs[:, 0:128] (f32 -> bf16)
  #pragma unroll
  for (int e = 0; e < 8; ++e) {
    int idx = tid + 256 * e;                         // float4 index, 2048 total
    int row = idx >> 5, c4 = idx & 31;
    int m = m0 + row; if (m >= NN) m = NN - 1;
    float4 v = *(const float4*)(ctx + (size_t)m * 128 + c4 * 4);
    ushort4 b;
    b.x = f2bf(v.x); b.y = f2bf(v.y); b.z = f2bf(v.z); b.w = f2bf(v.w);
    *(ushort4*)&xs[row][c4 * 4] = b;
  }
  // stage nf -> xs[:, 128:256] (already bf16)
  #pragma unroll
  for (int e = 0; e < 4; ++e) {
    int idx = tid + 256 * e;                         // uint4 index, 1024 total
    int row = idx >> 4, c8 = idx & 15;
    int m = m0 + row; if (m >= NN) m = NN - 1;
    uint4 v = *(const uint4*)(nfb + (size_t)m * 128 + c8 * 8);
    *(uint4*)&xs[row][128 + c8 * 8] = v;
  }
  __syncthreads();
  int wid = tid >> 6, lane = tid & 63;
  int wm = wid >> 1, wn = wid & 1;
  int l15 = lane & 15, lg = lane >> 4;
  // ---- layer 1: [64x256] @ [256x128]
  f32x4 acc[2][4];
  #pragma unroll
  for (int mf = 0; mf < 2; ++mf)
    #pragma unroll
    for (int nf = 0; nf < 4; ++nf) acc[mf][nf] = (f32x4){0.f, 0.f, 0.f, 0.f};
  for (int ks = 0; ks < 8; ++ks) {
    short8v a[2], b[4];
    #pragma unroll
    for (int mf = 0; mf < 2; ++mf)
      a[mf] = *(const short8v*)&xs[wm * 32 + mf * 16 + l15][ks * 32 + lg * 8];
    #pragma unroll
    for (int nf = 0; nf < 4; ++nf) {
      int n = wn * 64 + nf * 16 + l15;
      b[nf] = *(const short8v*)(w1t + (size_t)n * 256 + ks * 32 + lg * 8);
    }
    #pragma unroll
    for (int mf = 0; mf < 2; ++mf)
      #pragma unroll
      for (int nf = 0; nf < 4; ++nf)
        acc[mf][nf] = __builtin_amdgcn_mfma_f32_16x16x32_bf16(a[mf], b[nf], acc[mf][nf], 0, 0, 0);
  }
  // relu + bias -> h1s (bf16)
  {
    float b1n[4];
    #pragma unroll
    for (int nf = 0; nf < 4; ++nf) b1n[nf] = b1[wn * 64 + nf * 16 + l15];
    #pragma unroll
    for (int mf = 0; mf < 2; ++mf)
      #pragma unroll
      for (int nf = 0; nf < 4; ++nf)
        #pragma unroll
        for (int r = 0; r < 4; ++r) {
          int row = wm * 32 + mf * 16 + lg * 4 + r;
          int col = wn * 64 + nf * 16 + l15;
          float h = fmaxf(acc[mf][nf][r] + b1n[nf], 0.f);
          h1s[row][col] = f2bf(h);
        }
  }
  __syncthreads();
  // ---- layer 2: [64x128] @ [128x128]
  f32x4 acc2[2][4];
  #pragma unroll
  for (int mf = 0; mf < 2; ++mf)
    #pragma unroll
    for (int nf = 0; nf < 4; ++nf) acc2[mf][nf] = (f32x4){0.f, 0.f, 0.f, 0.f};
  for (int ks = 0; ks < 4; ++ks) {
    short8v a[2], b[4];
    #pragma unroll
    for (int mf = 0; mf < 2; ++mf)
      a[mf] = *(const short8v*)&h1s[wm * 32 + mf * 16 + l15][ks * 32 + lg * 8];
    #pragma unroll
    for (int nf = 0; nf < 4; ++nf) {
      int n = wn * 64 + nf * 16 + l15;
      b[nf] = *(const short8v*)(w2t + (size_t)n * 128 + ks * 32 + lg * 8);
    }
    #pragma unroll
    for (int mf = 0; mf < 2; ++mf)
      #pragma unroll
      for (int nf = 0; nf < 4; ++nf)
        acc2[mf][nf] = __builtin_amdgcn_mfma_f32_16x16x32_bf16(a[mf], b[nf], acc2[mf][nf], 0, 0, 0);
  }
  // epilogue: relu(h2 + b2) -> out, BN partials
  {
    float b2n[4];
    #pragma unroll
    for (int nf = 0; nf < 4; ++nf) b2n[nf] = b2[wn * 64 + nf * 16 + l15];
    float fsum[4] = {0.f, 0.f, 0.f, 0.f}, fsq[4] = {0.f, 0.f, 0.f, 0.f};
    #pragma unroll
    for (int mf = 0; mf < 2; ++mf)
      #pragma unroll
      for (int nf = 0; nf < 4; ++nf)
        #pragma unroll
        for (int r = 0; r < 4; ++r) {
          int m = m0 + wm * 32 + mf * 16 + lg * 4 + r;
          int n = wn * 64 + nf * 16 + l15;
          float h = fmaxf(acc2[mf][nf][r] + b2n[nf], 0.f);
          if (m < NN) {
            out[(size_t)m * 128 + n] = h;
            fsum[nf] += h;
            fsq[nf] += h * h;
          }
        }
    #pragma unroll
    for (int nf = 0; nf < 4; ++nf) {
      int n = wn * 64 + nf * 16 + l15;
      atomicAdd(&bns[n], fsum[nf]);
      atomicAdd(&bnq[n], fsq[nf]);
    }
  }
  __syncthreads();
  if (tid < 128) {
    atomicAdd(&bn_sum[tid], bns[tid]);
    atomicAdd(&bn_sumsq[tid], bnq[tid]);
  }
}

// ---------------------------------------------------------------- BN stats + normalize
__global__ __launch_bounds__(128) void k_bnstats(const float* __restrict__ bn_sum,
    const float* __restrict__ bn_sumsq, float* __restrict__ mean,
    float* __restrict__ istd) {
  int t = threadIdx.x;
  float mu = bn_sum[t] / (float)NN;
  float var = bn_sumsq[t] / (float)NN - mu * mu;
  var = fmaxf(var, 0.f);
  mean[t] = mu;
  istd[t] = 1.f / sqrtf(var + 1e-5f);
}

__global__ __launch_bounds__(256) void k_bnorm(float* __restrict__ out,
    const float* __restrict__ mean, const float* __restrict__ istd,
    const float* __restrict__ gamma, const float* __restrict__ beta) {
  int idx = blockIdx.x * 256 + threadIdx.x;          // float4 index, exact cover
  float4* p = (float4*)out;
  float4 v = p[idx];
  int f = (idx & 31) << 2;
  v.x = gamma[f + 0] * (v.x - mean[f + 0]) * istd[f + 0] + beta[f + 0];
  v.y = gamma[f + 1] * (v.y - mean[f + 1]) * istd[f + 1] + beta[f + 1];
  v.z = gamma[f + 2] * (v.z - mean[f + 2]) * istd[f + 2] + beta[f + 2];
  v.w = gamma[f + 3] * (v.w - mean[f + 3]) * istd[f + 3] + beta[f + 3];
  p[idx] = v;
}

// ----------------------------------------------------------------
extern "C" void kernel_launch(void* const* d_in, const int* in_sizes, int n_in,
                              void* d_out, int out_size, void* d_ws, size_t ws_size,
                              hipStream_t stream) {
  (void)in_sizes; (void)n_in; (void)out_size; (void)ws_size;
  const float* nf    = (const float*)d_in[0];
  const int*   src   = (const int*)d_in[1];
  const int*   dst   = (const int*)d_in[2];
  const float* wed   = (const float*)d_in[3];
  const float* wes   = (const float*)d_in[4];
  const float* be    = (const float*)d_in[5];
  const float* wp    = (const float*)d_in[6];
  const float* bp    = (const float*)d_in[7];
  const float* w1    = (const float*)d_in[8];
  const float* b1    = (const float*)d_in[9];
  const float* w2    = (const float*)d_in[10];
  const float* b2    = (const float*)d_in[11];
  const float* gamma = (const float*)d_in[12];
  const float* beta  = (const float*)d_in[13];
  float* out = (float*)d_out;
  char* ws = (char*)d_ws;

  unsigned short* hvb  = (unsigned short*)(ws + HVB_OFF);
  unsigned short* nfb  = (unsigned short*)(ws + NFB_OFF);
  float* ld    = (float*)(ws + LD_OFF);
  float* ls    = (float*)(ws + LS_OFF);
  int*   start = (int*)(ws + START_OFF);
  int*   cur   = (int*)(ws + CUR_OFF);
  int*   eid   = (int*)(ws + EID_OFF);
  unsigned short* w1t = (unsigned short*)(ws + W1T_OFF);
  unsigned short* w2t = (unsigned short*)(ws + W2T_OFF);
  unsigned short* wpt = (unsigned short*)(ws + WPT_OFF);
  int*   count = (int*)(ws + COUNT_OFF);
  int*   cursor= (int*)(ws + CURSOR_OFF);
  float* bsum  = (float*)(ws + BSUM_OFF);
  float* bsq   = (float*)(ws + BSQ_OFF);
  float* mean  = (float*)(ws + MEAN_OFF);
  float* istd  = (float*)(ws + ISTD_OFF);

  hipMemsetAsync(ws + COUNT_OFF, 0, ZERO_LEN, stream);

  k_cast_nf<<<6250, 256, 0, stream>>>(nf, nfb);
  k_prep_w<<<256, 256, 0, stream>>>(w1, w2, wp, w1t, w2t, wpt);
  k_dots<<<12500, 256, 0, stream>>>(nf, wed, wes, ld, ls);
  k_count<<<EE / 256, 256, 0, stream>>>(dst, count);
  k_offsets<<<(NN + 255) / 256, 256, 0, stream>>>(count, start, cur, cursor);
  k_fill<<<EE / 256, 256, 0, stream>>>(dst, cur, eid);
  k_hv2<<<(NN + 63) / 64, 256, 0, stream>>>(nfb, wpt, bp, hvb);
  k_agg<<<12500, 256, 0, stream>>>(hvb, ld, ls, src, be, start, count, eid, out);
  k_mlp2<<<(NN + 63) / 64, 256, 0, stream>>>(out, nfb, w1t, b1, w2t, b2, out, bsum, bsq);
  k_bnstats<<<1, 128, 0, stream>>>(bsum, bsq, mean, istd);
  k_bnorm<<<(NN * DD / 4) / 256, 256, 0, stream>>>(out, mean, istd, gamma, beta);
}

// Round 3
// 332.811 us; speedup vs baseline: 1.9843x; 1.5582x over previous
//
#include <hip/hip_runtime.h>
#include <math.h>

#define NN 50000
#define EE 1600000
#define DD 128
#define NB 98            // buckets of 512 nodes
#define BKT_CAP 18432    // bucket LDS capacity (mean 16384, sigma ~127)

typedef __attribute__((ext_vector_type(8))) short short8v;
typedef __attribute__((ext_vector_type(4))) float f32x4;

// workspace layout (bytes)
#define HVB_OFF     0            // [NN*128] bf16 = 12,800,000
#define BIN_OFF     12800000     // [EE] u32 = 6,400,000
#define SRCS_OFF    19200000     // [EE] u16 = 3,200,000
#define LD_OFF      22400000     // [NN] f32
#define LS_OFF      22600000     // [NN] f32
#define START_OFF   22800000     // [NN] i32
#define CNTN_OFF    23000000     // [NN] i32
#define W1T_OFF     23200000     // [128*256] bf16
#define W2T_OFF     23265536     // [128*128] bf16
#define WPT_OFF     23298304     // [128*128] bf16
#define BKT_OFF     23331072     // [128] i32 bucket_count (zeroed)
#define BKB_OFF     23331584     // [128] i32 bucket_base
#define BKC_OFF     23332096     // [128] i32 bucket_cur
#define BSUM_OFF    23332608     // [128] f32 (zeroed)
#define BSQ_OFF     23333120     // [128] f32 (zeroed)
#define MEAN_OFF    23333632     // [128] f32
#define ISTD_OFF    23334144     // [128] f32
#define ZERO_OFF    BKT_OFF
#define ZERO_LEN    2560         // BKT+BKB+BKC+BSUM+BSQ

__device__ __forceinline__ unsigned short f2bf(float f) {
  union { float f; unsigned u; } v; v.f = f;
  unsigned r = v.u + 0x7FFFu + ((v.u >> 16) & 1u);   // round-to-nearest-even
  return (unsigned short)(r >> 16);
}

// ---------------------------------------------------------------- prep: weight transposes (to [n][k] bf16)
__global__ __launch_bounds__(256) void k_prep_w(const float* __restrict__ w1,
    const float* __restrict__ w2, const float* __restrict__ wp,
    unsigned short* __restrict__ w1t, unsigned short* __restrict__ w2t,
    unsigned short* __restrict__ wpt) {
  int t = blockIdx.x * 256 + threadIdx.x;            // 0..65535
  if (t < 32768) {
    int n = t & 127, k = t >> 7;                     // k 0..255
    w1t[n * 256 + k] = f2bf(w1[(size_t)k * 128 + n]);
  } else if (t < 49152) {
    int i = t - 32768; int n = i & 127, k = i >> 7;
    w2t[n * 128 + k] = f2bf(w2[(size_t)k * 128 + n]);
  } else {
    int i = t - 49152; int n = i & 127, k = i >> 7;
    wpt[n * 128 + k] = f2bf(wp[(size_t)k * 128 + n]);
  }
}

// ---------------------------------------------------------------- per-node dots
__global__ __launch_bounds__(256) void k_dots(const float* __restrict__ nf,
    const float* __restrict__ wd, const float* __restrict__ wsrc,
    float* __restrict__ ld, float* __restrict__ ls) {
  int wid = (blockIdx.x * 256 + threadIdx.x) >> 6;
  int lane = threadIdx.x & 63;
  if (wid >= NN) return;
  float2 x = ((const float2*)(nf + (size_t)wid * DD))[lane];
  float2 a = ((const float2*)wd)[lane];
  float2 b = ((const float2*)wsrc)[lane];
  float pa = x.x * a.x + x.y * a.y;
  float pb = x.x * b.x + x.y * b.y;
  #pragma unroll
  for (int o = 32; o; o >>= 1) { pa += __shfl_xor(pa, o); pb += __shfl_xor(pb, o); }
  if (lane == 0) { ld[wid] = pa; ls[wid] = pb; }
}

// ---------------------------------------------------------------- sort S1: bucket histogram
__global__ __launch_bounds__(256) void k_bhist(const int* __restrict__ dst,
                                               int* __restrict__ bkt) {
  __shared__ int h[128];
  int tid = threadIdx.x;
  if (tid < 128) h[tid] = 0;
  __syncthreads();
  for (int e = blockIdx.x * 256 + tid; e < EE; e += 512 * 256)
    atomicAdd(&h[dst[e] >> 9], 1);
  __syncthreads();
  if (tid < 128 && h[tid]) atomicAdd(&bkt[tid], h[tid]);
}

// ---------------------------------------------------------------- sort S2: bucket scan
__global__ __launch_bounds__(128) void k_bscan(const int* __restrict__ bkt,
    int* __restrict__ bkb, int* __restrict__ bkc) {
  __shared__ int sc[128];
  int tid = threadIdx.x;
  int c = (tid < NB) ? bkt[tid] : 0;
  sc[tid] = c;
  __syncthreads();
  for (int off = 1; off < 128; off <<= 1) {
    int v = sc[tid] + ((tid >= off) ? sc[tid - off] : 0);
    __syncthreads();
    sc[tid] = v;
    __syncthreads();
  }
  int base = sc[tid] - c;                            // exclusive
  bkb[tid] = base;
  bkc[tid] = base;
}

// ---------------------------------------------------------------- sort S3: bin edges (packed dst<<16|src) to buckets
__global__ __launch_bounds__(256) void k_bin(const int* __restrict__ src,
    const int* __restrict__ dst, int* __restrict__ bkc,
    unsigned* __restrict__ bin) {
  __shared__ unsigned slot[8192];
  __shared__ int hist[128], sc[128], loff[128], lcur[128], gbase[128];
  int tid = threadIdx.x;
  int tbase = blockIdx.x * 8192;
  int tlen = min(8192, EE - tbase);
  unsigned pk[32];
  if (tid < 128) hist[tid] = 0;
  __syncthreads();
  #pragma unroll
  for (int k = 0; k < 32; ++k) {
    int i = k * 256 + tid;
    if (i < tlen) {
      int e = tbase + i;
      pk[k] = ((unsigned)dst[e] << 16) | (unsigned)src[e];
      atomicAdd(&hist[pk[k] >> 25], 1);
    }
  }
  __syncthreads();
  // exclusive scan of 128 bucket counts
  if (tid < 128) sc[tid] = hist[tid];
  __syncthreads();
  for (int off = 1; off < 128; off <<= 1) {
    int v = 0;
    if (tid < 128) v = sc[tid] + ((tid >= off) ? sc[tid - off] : 0);
    __syncthreads();
    if (tid < 128) sc[tid] = v;
    __syncthreads();
  }
  if (tid < 128) { loff[tid] = sc[tid] - hist[tid]; lcur[tid] = sc[tid] - hist[tid]; }
  __syncthreads();
  #pragma unroll
  for (int k = 0; k < 32; ++k) {
    int i = k * 256 + tid;
    if (i < tlen) {
      int r = atomicAdd(&lcur[pk[k] >> 25], 1);
      slot[r] = pk[k];
    }
  }
  __syncthreads();
  if (tid < 128) gbase[tid] = hist[tid] ? atomicAdd(&bkc[tid], hist[tid]) : 0;
  __syncthreads();
  #pragma unroll
  for (int k = 0; k < 32; ++k) {
    int i = k * 256 + tid;
    if (i < tlen) {
      unsigned p = slot[i];
      int b = p >> 25;
      bin[gbase[b] + (i - loff[b])] = p;
    }
  }
}

// ---------------------------------------------------------------- sort S4: per-bucket node sort, emit srcs + start/count
__global__ __launch_bounds__(256) void k_bsort(const unsigned* __restrict__ bin,
    const int* __restrict__ bkt, const int* __restrict__ bkb,
    unsigned short* __restrict__ srcs, int* __restrict__ start,
    int* __restrict__ cntn) {
  __shared__ unsigned eL[BKT_CAP];
  __shared__ unsigned short outL[BKT_CAP];
  __shared__ int hist[512], scA[512], cur[512];
  int tid = threadIdx.x;
  int b = blockIdx.x;
  int base = bkb[b];
  int cnt = bkt[b];
  int node0 = b << 9;
  int nnb = min(512, NN - node0);
  bool fits = (cnt <= BKT_CAP);
  for (int i = tid; i < 512; i += 256) hist[i] = 0;
  __syncthreads();
  if (fits) {
    for (int i = tid; i < cnt; i += 256) {
      unsigned p = bin[base + i];
      eL[i] = p;
      atomicAdd(&hist[(p >> 16) & 511], 1);
    }
  } else {
    for (int i = tid; i < cnt; i += 256)
      atomicAdd(&hist[(bin[base + i] >> 16) & 511], 1);
  }
  __syncthreads();
  // exclusive scan over 512
  for (int i = tid; i < 512; i += 256) scA[i] = hist[i];
  __syncthreads();
  for (int off = 1; off < 512; off <<= 1) {
    int v0 = scA[tid] + ((tid >= off) ? scA[tid - off] : 0);
    int i1 = tid + 256;
    int v1 = scA[i1] + ((i1 >= off) ? scA[i1 - off] : 0);
    __syncthreads();
    scA[tid] = v0; scA[i1] = v1;
    __syncthreads();
  }
  for (int i = tid; i < 512; i += 256) {
    int ex = scA[i] - hist[i];
    cur[i] = ex;
    if (i < nnb) { start[node0 + i] = base + ex; cntn[node0 + i] = hist[i]; }
  }
  __syncthreads();
  if (fits) {
    for (int i = tid; i < cnt; i += 256) {
      unsigned p = eL[i];
      int r = atomicAdd(&cur[(p >> 16) & 511], 1);
      outL[r] = (unsigned short)(p & 0xFFFFu);
    }
    __syncthreads();
    for (int i = tid; i < cnt; i += 256) srcs[base + i] = outL[i];
  } else {
    for (int i = tid; i < cnt; i += 256) {
      unsigned p = bin[base + i];
      int r = atomicAdd(&cur[(p >> 16) & 511], 1);
      srcs[base + r] = (unsigned short)(p & 0xFFFFu);
    }
  }
}

// ---------------------------------------------------------------- hv = bf16( nf @ w_proj + b_proj )  [MFMA]
__global__ __launch_bounds__(256) void k_hv2(const float* __restrict__ nf,
    const unsigned short* __restrict__ wpt, const float* __restrict__ bp,
    unsigned short* __restrict__ hvb) {
  __shared__ unsigned short xs[64][136];
  int tid = threadIdx.x;
  int m0 = blockIdx.x * 64;
  #pragma unroll
  for (int e = 0; e < 8; ++e) {
    int idx = tid + 256 * e;                         // float4 index, 2048 total
    int row = idx >> 5, c4 = idx & 31;
    int m = m0 + row; if (m >= NN) m = NN - 1;
    float4 v = *(const float4*)(nf + (size_t)m * 128 + c4 * 4);
    ushort4 bb;
    bb.x = f2bf(v.x); bb.y = f2bf(v.y); bb.z = f2bf(v.z); bb.w = f2bf(v.w);
    *(ushort4*)&xs[row][c4 * 4] = bb;
  }
  __syncthreads();
  int wid = tid >> 6, lane = tid & 63;
  int wm = wid >> 1, wn = wid & 1;
  int l15 = lane & 15, lg = lane >> 4;
  f32x4 acc[2][4];
  #pragma unroll
  for (int mf = 0; mf < 2; ++mf)
    #pragma unroll
    for (int nf2 = 0; nf2 < 4; ++nf2) acc[mf][nf2] = (f32x4){0.f, 0.f, 0.f, 0.f};
  for (int ks = 0; ks < 4; ++ks) {
    short8v a[2], b[4];
    #pragma unroll
    for (int mf = 0; mf < 2; ++mf)
      a[mf] = *(const short8v*)&xs[wm * 32 + mf * 16 + l15][ks * 32 + lg * 8];
    #pragma unroll
    for (int nf2 = 0; nf2 < 4; ++nf2) {
      int n = wn * 64 + nf2 * 16 + l15;
      b[nf2] = *(const short8v*)(wpt + (size_t)n * 128 + ks * 32 + lg * 8);
    }
    #pragma unroll
    for (int mf = 0; mf < 2; ++mf)
      #pragma unroll
      for (int nf2 = 0; nf2 < 4; ++nf2)
        acc[mf][nf2] = __builtin_amdgcn_mfma_f32_16x16x32_bf16(a[mf], b[nf2], acc[mf][nf2], 0, 0, 0);
  }
  float bpn[4];
  #pragma unroll
  for (int nf2 = 0; nf2 < 4; ++nf2) bpn[nf2] = bp[wn * 64 + nf2 * 16 + l15];
  #pragma unroll
  for (int mf = 0; mf < 2; ++mf)
    #pragma unroll
    for (int nf2 = 0; nf2 < 4; ++nf2)
      #pragma unroll
      for (int r = 0; r < 4; ++r) {
        int m = m0 + wm * 32 + mf * 16 + lg * 4 + r;
        int n = wn * 64 + nf2 * 16 + l15;
        if (m < NN) hvb[(size_t)m * 128 + n] = f2bf(acc[mf][nf2][r] + bpn[nf2]);
      }
}

// ---------------------------------------------------------------- edge softmax + aggregate + ELU
// one wave per node; 2 edges per PV iteration (half-wave each)
__global__ __launch_bounds__(256) void k_agg(const unsigned short* __restrict__ hvb,
    const float* __restrict__ ld, const float* __restrict__ ls,
    const float* __restrict__ be_p, const int* __restrict__ start,
    const int* __restrict__ cntn, const unsigned short* __restrict__ srcs,
    float* __restrict__ context) {
  int wid = (blockIdx.x * 256 + threadIdx.x) >> 6;
  int lane = threadIdx.x & 63;
  if (wid >= NN) return;
  int cnt = cntn[wid];
  int half = lane >> 5, l31 = lane & 31;
  float4 acc = make_float4(0.f, 0.f, 0.f, 0.f);      // features l31*4 .. +3
  if (cnt == 0) {
    if (half == 0) ((float4*)(context + (size_t)wid * DD))[l31] = acc;
    return;
  }
  int s = start[wid];
  float base = ld[wid] + be_p[0];
  float m = -INFINITY;
  float dsum = 0.f;
  for (int c0 = 0; c0 < cnt; c0 += 64) {
    int len = min(64, cnt - c0);
    float lg = -INFINITY;
    int sv = 0;
    if (lane < len) {
      sv = srcs[s + c0 + lane];
      float l = base + ls[sv];
      lg = (l >= 0.f) ? l : 0.01f * l;
    }
    float cm = lg;
    #pragma unroll
    for (int o = 32; o; o >>= 1) cm = fmaxf(cm, __shfl_xor(cm, o));
    float nm = fmaxf(m, cm);
    float scale = expf(m - nm);
    acc.x *= scale; acc.y *= scale; acc.z *= scale; acc.w *= scale;
    dsum *= scale;
    float ev = (lane < len) ? expf(lg - nm) : 0.f;
    dsum += ev;
    for (int j = 0; j < len; j += 2) {
      int jj = j + half;
      float evj = __shfl(ev, jj);
      int svj = __shfl(sv, jj);
      if (jj < len) {
        uint2 u = *(const uint2*)(hvb + (size_t)svj * DD + l31 * 4);
        union { unsigned u; float f; } f0, f1, f2, f3;
        f0.u = u.x << 16; f1.u = u.x & 0xFFFF0000u;
        f2.u = u.y << 16; f3.u = u.y & 0xFFFF0000u;
        acc.x += evj * f0.f; acc.y += evj * f1.f;
        acc.z += evj * f2.f; acc.w += evj * f3.f;
      }
    }
    m = nm;
  }
  // combine the two half-wave partials + reduce dsum
  acc.x += __shfl_xor(acc.x, 32); acc.y += __shfl_xor(acc.y, 32);
  acc.z += __shfl_xor(acc.z, 32); acc.w += __shfl_xor(acc.w, 32);
  #pragma unroll
  for (int o = 32; o; o >>= 1) dsum += __shfl_xor(dsum, o);
  float r = 1.f / dsum;
  acc.x *= r; acc.y *= r; acc.z *= r; acc.w *= r;
  acc.x = (acc.x > 0.f) ? acc.x : expm1f(acc.x);
  acc.y = (acc.y > 0.f) ? acc.y : expm1f(acc.y);
  acc.z = (acc.z > 0.f) ? acc.z : expm1f(acc.z);
  acc.w = (acc.w > 0.f) ? acc.w : expm1f(acc.w);
  if (half == 0) ((float4*)(context + (size_t)wid * DD))[l31] = acc;
}

// ---------------------------------------------------------------- fused MLP [MFMA] + BN partials
// ctx aliases out: each block reads only its own rows (before overwriting them in epilogue).
__global__ __launch_bounds__(256) void k_mlp2(const float* ctx,
    const float* __restrict__ nf,
    const unsigned short* __restrict__ w1t, const float* __restrict__ b1,
    const unsigned short* __restrict__ w2t, const float* __restrict__ b2,
    float* out, float* __restrict__ bn_sum, float* __restrict__ bn_sumsq) {
  __shared__ unsigned short xs[64][264];
  __shared__ unsigned short h1s[64][136];
  __shared__ float bns[128], bnq[128];
  int tid = threadIdx.x;
  int m0 = blockIdx.x * 64;
  if (tid < 128) { bns[tid] = 0.f; bnq[tid] = 0.f; }
  #pragma unroll
  for (int e = 0; e < 8; ++e) {
    int idx = tid + 256 * e;                         // float4 index, 2048 total
    int row = idx >> 5, c4 = idx & 31;
    int m = m0 + row; if (m >= NN) m = NN - 1;
    float4 v = *(const float4*)(ctx + (size_t)m * 128 + c4 * 4);
    ushort4 bb;
    bb.x = f2bf(v.x); bb.y = f2bf(v.y); bb.z = f2bf(v.z); bb.w = f2bf(v.w);
    *(ushort4*)&xs[row][c4 * 4] = bb;
    float4 w = *(const float4*)(nf + (size_t)m * 128 + c4 * 4);
    ushort4 cc;
    cc.x = f2bf(w.x); cc.y = f2bf(w.y); cc.z = f2bf(w.z); cc.w = f2bf(w.w);
    *(ushort4*)&xs[row][128 + c4 * 4] = cc;
  }
  __syncthreads();
  int wid = tid >> 6, lane = tid & 63;
  int wm = wid >> 1, wn = wid & 1;
  int l15 = lane & 15, lg = lane >> 4;
  f32x4 acc[2][4];
  #pragma unroll
  for (int mf = 0; mf < 2; ++mf)
    #pragma unroll
    for (int nf2 = 0; nf2 < 4; ++nf2) acc[mf][nf2] = (f32x4){0.f, 0.f, 0.f, 0.f};
  for (int ks = 0; ks < 8; ++ks) {
    short8v a[2], b[4];
    #pragma unroll
    for (int mf = 0; mf < 2; ++mf)
      a[mf] = *(const short8v*)&xs[wm * 32 + mf * 16 + l15][ks * 32 + lg * 8];
    #pragma unroll
    for (int nf2 = 0; nf2 < 4; ++nf2) {
      int n = wn * 64 + nf2 * 16 + l15;
      b[nf2] = *(const short8v*)(w1t + (size_t)n * 256 + ks * 32 + lg * 8);
    }
    #pragma unroll
    for (int mf = 0; mf < 2; ++mf)
      #pragma unroll
      for (int nf2 = 0; nf2 < 4; ++nf2)
        acc[mf][nf2] = __builtin_amdgcn_mfma_f32_16x16x32_bf16(a[mf], b[nf2], acc[mf][nf2], 0, 0, 0);
  }
  {
    float b1n[4];
    #pragma unroll
    for (int nf2 = 0; nf2 < 4; ++nf2) b1n[nf2] = b1[wn * 64 + nf2 * 16 + l15];
    #pragma unroll
    for (int mf = 0; mf < 2; ++mf)
      #pragma unroll
      for (int nf2 = 0; nf2 < 4; ++nf2)
        #pragma unroll
        for (int r = 0; r < 4; ++r) {
          int row = wm * 32 + mf * 16 + lg * 4 + r;
          int col = wn * 64 + nf2 * 16 + l15;
          float h = fmaxf(acc[mf][nf2][r] + b1n[nf2], 0.f);
          h1s[row][col] = f2bf(h);
        }
  }
  __syncthreads();
  f32x4 acc2[2][4];
  #pragma unroll
  for (int mf = 0; mf < 2; ++mf)
    #pragma unroll
    for (int nf2 = 0; nf2 < 4; ++nf2) acc2[mf][nf2] = (f32x4){0.f, 0.f, 0.f, 0.f};
  for (int ks = 0; ks < 4; ++ks) {
    short8v a[2], b[4];
    #pragma unroll
    for (int mf = 0; mf < 2; ++mf)
      a[mf] = *(const short8v*)&h1s[wm * 32 + mf * 16 + l15][ks * 32 + lg * 8];
    #pragma unroll
    for (int nf2 = 0; nf2 < 4; ++nf2) {
      int n = wn * 64 + nf2 * 16 + l15;
      b[nf2] = *(const short8v*)(w2t + (size_t)n * 128 + ks * 32 + lg * 8);
    }
    #pragma unroll
    for (int mf = 0; mf < 2; ++mf)
      #pragma unroll
      for (int nf2 = 0; nf2 < 4; ++nf2)
        acc2[mf][nf2] = __builtin_amdgcn_mfma_f32_16x16x32_bf16(a[mf], b[nf2], acc2[mf][nf2], 0, 0, 0);
  }
  {
    float b2n[4];
    #pragma unroll
    for (int nf2 = 0; nf2 < 4; ++nf2) b2n[nf2] = b2[wn * 64 + nf2 * 16 + l15];
    float fsum[4] = {0.f, 0.f, 0.f, 0.f}, fsq[4] = {0.f, 0.f, 0.f, 0.f};
    #pragma unroll
    for (int mf = 0; mf < 2; ++mf)
      #pragma unroll
      for (int nf2 = 0; nf2 < 4; ++nf2)
        #pragma unroll
        for (int r = 0; r < 4; ++r) {
          int m = m0 + wm * 32 + mf * 16 + lg * 4 + r;
          int n = wn * 64 + nf2 * 16 + l15;
          float h = fmaxf(acc2[mf][nf2][r] + b2n[nf2], 0.f);
          if (m < NN) {
            out[(size_t)m * 128 + n] = h;
            fsum[nf2] += h;
            fsq[nf2] += h * h;
          }
        }
    #pragma unroll
    for (int nf2 = 0; nf2 < 4; ++nf2) {
      int n = wn * 64 + nf2 * 16 + l15;
      atomicAdd(&bns[n], fsum[nf2]);
      atomicAdd(&bnq[n], fsq[nf2]);
    }
  }
  __syncthreads();
  if (tid < 128) {
    atomicAdd(&bn_sum[tid], bns[tid]);
    atomicAdd(&bn_sumsq[tid], bnq[tid]);
  }
}

// ---------------------------------------------------------------- BN stats + normalize
__global__ __launch_bounds__(128) void k_bnstats(const float* __restrict__ bn_sum,
    const float* __restrict__ bn_sumsq, float* __restrict__ mean,
    float* __restrict__ istd) {
  int t = threadIdx.x;
  float mu = bn_sum[t] / (float)NN;
  float var = bn_sumsq[t] / (float)NN - mu * mu;
  var = fmaxf(var, 0.f);
  mean[t] = mu;
  istd[t] = 1.f / sqrtf(var + 1e-5f);
}

__global__ __launch_bounds__(256) void k_bnorm(float* __restrict__ out,
    const float* __restrict__ mean, const float* __restrict__ istd,
    const float* __restrict__ gamma, const float* __restrict__ beta) {
  int idx = blockIdx.x * 256 + threadIdx.x;
  float4* p = (float4*)out;
  float4 v = p[idx];
  int f = (idx & 31) << 2;
  v.x = gamma[f + 0] * (v.x - mean[f + 0]) * istd[f + 0] + beta[f + 0];
  v.y = gamma[f + 1] * (v.y - mean[f + 1]) * istd[f + 1] + beta[f + 1];
  v.z = gamma[f + 2] * (v.z - mean[f + 2]) * istd[f + 2] + beta[f + 2];
  v.w = gamma[f + 3] * (v.w - mean[f + 3]) * istd[f + 3] + beta[f + 3];
  p[idx] = v;
}

// ----------------------------------------------------------------
extern "C" void kernel_launch(void* const* d_in, const int* in_sizes, int n_in,
                              void* d_out, int out_size, void* d_ws, size_t ws_size,
                              hipStream_t stream) {
  (void)in_sizes; (void)n_in; (void)out_size; (void)ws_size;
  const float* nf    = (const float*)d_in[0];
  const int*   src   = (const int*)d_in[1];
  const int*   dst   = (const int*)d_in[2];
  const float* wed   = (const float*)d_in[3];
  const float* wes   = (const float*)d_in[4];
  const float* be    = (const float*)d_in[5];
  const float* wp    = (const float*)d_in[6];
  const float* bp    = (const float*)d_in[7];
  const float* w1    = (const float*)d_in[8];
  const float* b1    = (const float*)d_in[9];
  const float* w2    = (const float*)d_in[10];
  const float* b2    = (const float*)d_in[11];
  const float* gamma = (const float*)d_in[12];
  const float* beta  = (const float*)d_in[13];
  float* out = (float*)d_out;
  char* ws = (char*)d_ws;

  unsigned short* hvb  = (unsigned short*)(ws + HVB_OFF);
  unsigned*       bin  = (unsigned*)(ws + BIN_OFF);
  unsigned short* srcs = (unsigned short*)(ws + SRCS_OFF);
  float* ld    = (float*)(ws + LD_OFF);
  float* ls    = (float*)(ws + LS_OFF);
  int*   start = (int*)(ws + START_OFF);
  int*   cntn  = (int*)(ws + CNTN_OFF);
  unsigned short* w1t = (unsigned short*)(ws + W1T_OFF);
  unsigned short* w2t = (unsigned short*)(ws + W2T_OFF);
  unsigned short* wpt = (unsigned short*)(ws + WPT_OFF);
  int*   bkt   = (int*)(ws + BKT_OFF);
  int*   bkb   = (int*)(ws + BKB_OFF);
  int*   bkc   = (int*)(ws + BKC_OFF);
  float* bsum  = (float*)(ws + BSUM_OFF);
  float* bsq   = (float*)(ws + BSQ_OFF);
  float* mean  = (float*)(ws + MEAN_OFF);
  float* istd  = (float*)(ws + ISTD_OFF);

  hipMemsetAsync(ws + ZERO_OFF, 0, ZERO_LEN, stream);

  k_prep_w<<<256, 256, 0, stream>>>(w1, w2, wp, w1t, w2t, wpt);
  k_dots<<<12500, 256, 0, stream>>>(nf, wed, wes, ld, ls);
  k_bhist<<<512, 256, 0, stream>>>(dst, bkt);
  k_bscan<<<1, 128, 0, stream>>>(bkt, bkb, bkc);
  k_bin<<<196, 256, 0, stream>>>(src, dst, bkc, bin);
  k_bsort<<<NB, 256, 0, stream>>>(bin, bkt, bkb, srcs, start, cntn);
  k_hv2<<<(NN + 63) / 64, 256, 0, stream>>>(nf, wpt, bp, hvb);
  k_agg<<<12500, 256, 0, stream>>>(hvb, ld, ls, be, start, cntn, srcs, out);
  k_mlp2<<<(NN + 63) / 64, 256, 0, stream>>>(out, nf, w1t, b1, w2t, b2, out, bsum, bsq);
  k_bnstats<<<1, 128, 0, stream>>>(bsum, bsq, mean, istd);
  k_bnorm<<<(NN * DD / 4) / 256, 256, 0, stream>>>(out, mean, istd, gamma, beta);
}

// Round 5
// 288.949 us; speedup vs baseline: 2.2855x; 1.1518x over previous
//
#include <hip/hip_runtime.h>
#include <math.h>

#define NN 50000
#define EE 1600000
#define DD 128
#define NB 98            // buckets of 512 nodes
#define SLAB 18432       // slab capacity per bucket (mean 16384, +16 sigma)

typedef __attribute__((ext_vector_type(8))) short short8v;
typedef __attribute__((ext_vector_type(4))) float f32x4;
typedef __attribute__((ext_vector_type(2))) float floatx2;

// workspace layout (bytes)
#define HVB_OFF     0            // [NN*128] fp8 = 6,400,000
#define CTXB_OFF    6400000      // [NN*128] bf16 = 12,800,000
#define BIN_OFF     19200000     // [NB*SLAB] u32 = 7,225,344
#define SRCS_OFF    26425344     // [NB*SLAB] u16 = 3,612,672
#define LD_OFF      30038016     // [NN] f32
#define LS_OFF      30238016     // [NN] f32
#define START_OFF   30438016     // [NN] i32
#define CNTN_OFF    30638016     // [NN] i32
#define W1T_OFF     30838016     // [128*256] bf16
#define W2T_OFF     30903552     // [128*128] bf16
#define WPT_OFF     30936320     // [128*128] bf16
#define BKC_OFF     30969088     // [128] i32 (zeroed)
#define BSUM_OFF    30969600     // [128] f32 (zeroed)
#define BSQ_OFF     30970112     // [128] f32 (zeroed)
#define MEAN_OFF    30970624     // [128] f32
#define ISTD_OFF    30971136     // [128] f32
#define ZERO_OFF    BKC_OFF
#define ZERO_LEN    1536         // BKC+BSUM+BSQ

__device__ __forceinline__ unsigned short f2bf(float f) {
  union { float f; unsigned u; } v; v.f = f;
  unsigned r = v.u + 0x7FFFu + ((v.u >> 16) & 1u);   // round-to-nearest-even
  return (unsigned short)(r >> 16);
}

// ---------------------------------------------------------------- prep: weight transposes (to [n][k] bf16)
__global__ __launch_bounds__(256) void k_prep_w(const float* __restrict__ w1,
    const float* __restrict__ w2, const float* __restrict__ wp,
    unsigned short* __restrict__ w1t, unsigned short* __restrict__ w2t,
    unsigned short* __restrict__ wpt) {
  int t = blockIdx.x * 256 + threadIdx.x;            // 0..65535
  if (t < 32768) {
    int n = t & 127, k = t >> 7;                     // k 0..255
    w1t[n * 256 + k] = f2bf(w1[(size_t)k * 128 + n]);
  } else if (t < 49152) {
    int i = t - 32768; int n = i & 127, k = i >> 7;
    w2t[n * 128 + k] = f2bf(w2[(size_t)k * 128 + n]);
  } else {
    int i = t - 49152; int n = i & 127, k = i >> 7;
    wpt[n * 128 + k] = f2bf(wp[(size_t)k * 128 + n]);
  }
}

// ---------------------------------------------------------------- hv (fp8) + ld/ls, fused  [MFMA]
// swapped-operand MFMA: D.row <-> n (weight row), D.col <-> m. Lane holds 4
// consecutive features of one node -> pack one fp8 dword, direct store.
__global__ __launch_bounds__(256) void k_hv2(const float* __restrict__ nf,
    const unsigned short* __restrict__ wpt, const float* __restrict__ bp,
    const float* __restrict__ wed, const float* __restrict__ wes,
    float* __restrict__ ld, float* __restrict__ ls,
    unsigned char* __restrict__ hvb) {
  __shared__ unsigned short xs[64][136];
  int tid = threadIdx.x;
  int m0 = blockIdx.x * 64;
  int c4 = tid & 31;
  float4 wdv = *(const float4*)(wed + c4 * 4);
  float4 wsv = *(const float4*)(wes + c4 * 4);
  #pragma unroll
  for (int e = 0; e < 8; ++e) {
    int idx = tid + 256 * e;                         // float4 index, 2048 total
    int row = idx >> 5;
    int m = m0 + row;
    int mc = (m < NN) ? m : (NN - 1);
    float4 v = *(const float4*)(nf + (size_t)mc * 128 + c4 * 4);
    ushort4 bb;
    bb.x = f2bf(v.x); bb.y = f2bf(v.y); bb.z = f2bf(v.z); bb.w = f2bf(v.w);
    *(ushort4*)&xs[row][c4 * 4] = bb;
    float pa = v.x * wdv.x + v.y * wdv.y + v.z * wdv.z + v.w * wdv.w;
    float pb = v.x * wsv.x + v.y * wsv.y + v.z * wsv.z + v.w * wsv.w;
    #pragma unroll
    for (int o = 16; o; o >>= 1) { pa += __shfl_xor(pa, o); pb += __shfl_xor(pb, o); }
    if (c4 == 0 && m < NN) { ld[m] = pa; ls[m] = pb; }
  }
  __syncthreads();
  int wid = tid >> 6, lane = tid & 63;
  int wm = wid >> 1, wn = wid & 1;
  int l15 = lane & 15, lg = lane >> 4;
  f32x4 acc[4][2];                                   // [n-frag][m-frag]
  #pragma unroll
  for (int nf2 = 0; nf2 < 4; ++nf2)
    #pragma unroll
    for (int mf = 0; mf < 2; ++mf) acc[nf2][mf] = (f32x4){0.f, 0.f, 0.f, 0.f};
  for (int ks = 0; ks < 4; ++ks) {
    short8v aw[4], bx[2];
    #pragma unroll
    for (int nf2 = 0; nf2 < 4; ++nf2) {
      int n = wn * 64 + nf2 * 16 + l15;
      aw[nf2] = *(const short8v*)(wpt + (size_t)n * 128 + ks * 32 + lg * 8);
    }
    #pragma unroll
    for (int mf = 0; mf < 2; ++mf)
      bx[mf] = *(const short8v*)&xs[wm * 32 + mf * 16 + l15][ks * 32 + lg * 8];
    #pragma unroll
    for (int nf2 = 0; nf2 < 4; ++nf2)
      #pragma unroll
      for (int mf = 0; mf < 2; ++mf)
        acc[nf2][mf] = __builtin_amdgcn_mfma_f32_16x16x32_bf16(aw[nf2], bx[mf], acc[nf2][mf], 0, 0, 0);
  }
  #pragma unroll
  for (int nf2 = 0; nf2 < 4; ++nf2) {
    float4 bp4 = *(const float4*)(bp + wn * 64 + nf2 * 16 + lg * 4);
    #pragma unroll
    for (int mf = 0; mf < 2; ++mf) {
      int m = m0 + wm * 32 + mf * 16 + l15;
      if (m < NN) {
        int w = __builtin_amdgcn_cvt_pk_fp8_f32(acc[nf2][mf][0] + bp4.x,
                                                acc[nf2][mf][1] + bp4.y, 0, false);
        w = __builtin_amdgcn_cvt_pk_fp8_f32(acc[nf2][mf][2] + bp4.z,
                                            acc[nf2][mf][3] + bp4.w, w, true);
        *(int*)(hvb + (size_t)m * 128 + wn * 64 + nf2 * 16 + lg * 4) = w;
      }
    }
  }
}

// ---------------------------------------------------------------- sort S1: bin edges (packed dst<<16|src) into bucket slabs
__global__ __launch_bounds__(256) void k_bin(const int* __restrict__ src,
    const int* __restrict__ dst, int* __restrict__ bkc,
    unsigned* __restrict__ bin) {
  __shared__ unsigned slot[8192];
  __shared__ int hist[128], sc[128], loff[128], lcur[128], gbase[128];
  int tid = threadIdx.x;
  int tbase = blockIdx.x * 8192;
  int tlen = min(8192, EE - tbase);
  unsigned pk[32];
  if (tid < 128) hist[tid] = 0;
  __syncthreads();
  #pragma unroll
  for (int k = 0; k < 32; ++k) {
    int i = k * 256 + tid;
    if (i < tlen) {
      int e = tbase + i;
      pk[k] = ((unsigned)dst[e] << 16) | (unsigned)src[e];
      atomicAdd(&hist[pk[k] >> 25], 1);
    }
  }
  __syncthreads();
  if (tid < 128) sc[tid] = hist[tid];
  __syncthreads();
  for (int off = 1; off < 128; off <<= 1) {
    int v = 0;
    if (tid < 128) v = sc[tid] + ((tid >= off) ? sc[tid - off] : 0);
    __syncthreads();
    if (tid < 128) sc[tid] = v;
    __syncthreads();
  }
  if (tid < 128) { loff[tid] = sc[tid] - hist[tid]; lcur[tid] = sc[tid] - hist[tid]; }
  __syncthreads();
  #pragma unroll
  for (int k = 0; k < 32; ++k) {
    int i = k * 256 + tid;
    if (i < tlen) {
      int r = atomicAdd(&lcur[pk[k] >> 25], 1);
      slot[r] = pk[k];
    }
  }
  __syncthreads();
  if (tid < 128) gbase[tid] = hist[tid] ? atomicAdd(&bkc[tid], hist[tid]) : 0;
  __syncthreads();
  #pragma unroll
  for (int k = 0; k < 32; ++k) {
    int i = k * 256 + tid;
    if (i < tlen) {
      unsigned p = slot[i];
      int b = p >> 25;
      bin[(size_t)b * SLAB + gbase[b] + (i - loff[b])] = p;
    }
  }
}

// ---------------------------------------------------------------- sort S2: per-bucket node sort, emit srcs + start/count
__global__ __launch_bounds__(256) void k_bsort(const unsigned* __restrict__ bin,
    const int* __restrict__ bkc, unsigned short* __restrict__ srcs,
    int* __restrict__ start, int* __restrict__ cntn) {
  __shared__ unsigned eL[SLAB];
  __shared__ unsigned short outL[SLAB];
  __shared__ int hist[512], scA[512], cur[512];
  int tid = threadIdx.x;
  int b = blockIdx.x;
  int base = b * SLAB;
  int cnt = bkc[b];
  int node0 = b << 9;
  int nnb = min(512, NN - node0);
  for (int i = tid; i < 512; i += 256) hist[i] = 0;
  __syncthreads();
  for (int i = tid; i < cnt; i += 256) {
    unsigned p = bin[base + i];
    eL[i] = p;
    atomicAdd(&hist[(p >> 16) & 511], 1);
  }
  __syncthreads();
  for (int i = tid; i < 512; i += 256) scA[i] = hist[i];
  __syncthreads();
  for (int off = 1; off < 512; off <<= 1) {
    int v0 = scA[tid] + ((tid >= off) ? scA[tid - off] : 0);
    int i1 = tid + 256;
    int v1 = scA[i1] + ((i1 >= off) ? scA[i1 - off] : 0);
    __syncthreads();
    scA[tid] = v0; scA[i1] = v1;
    __syncthreads();
  }
  for (int i = tid; i < 512; i += 256) {
    int ex = scA[i] - hist[i];
    cur[i] = ex;
    if (i < nnb) { start[node0 + i] = base + ex; cntn[node0 + i] = hist[i]; }
  }
  __syncthreads();
  for (int i = tid; i < cnt; i += 256) {
    unsigned p = eL[i];
    int r = atomicAdd(&cur[(p >> 16) & 511], 1);
    outL[r] = (unsigned short)(p & 0xFFFFu);
  }
  __syncthreads();
  for (int i = tid; i < cnt; i += 256) srcs[base + i] = outL[i];
}

// ---------------------------------------------------------------- edge softmax + aggregate + ELU -> bf16 context
// one wave per node; 8 edges per PV iteration (8 lanes/edge, dwordx4 fp8 loads)
__global__ __launch_bounds__(256) void k_agg(const unsigned char* __restrict__ hvb,
    const float* __restrict__ ld, const float* __restrict__ ls,
    const float* __restrict__ be_p, const int* __restrict__ start,
    const int* __restrict__ cntn, const unsigned short* __restrict__ srcs,
    unsigned short* __restrict__ ctxb) {
  int wid = (blockIdx.x * 256 + threadIdx.x) >> 6;
  int lane = threadIdx.x & 63;
  if (wid >= NN) return;
  int cnt = cntn[wid];
  int l8 = lane & 7, e8 = lane >> 3;
  float acc[16];
  #pragma unroll
  for (int i = 0; i < 16; ++i) acc[i] = 0.f;
  float m = -INFINITY, dsum = 0.f;
  if (cnt > 0) {
    int s = start[wid];
    float base = ld[wid] + be_p[0];
    for (int c0 = 0; c0 < cnt; c0 += 64) {
      int len = min(64, cnt - c0);
      float lg = -INFINITY;
      int sv = 0;
      if (lane < len) {
        sv = srcs[s + c0 + lane];
        float l = base + ls[sv];
        lg = (l >= 0.f) ? l : 0.01f * l;
      }
      float cm = lg;
      #pragma unroll
      for (int o = 32; o; o >>= 1) cm = fmaxf(cm, __shfl_xor(cm, o));
      float nm = fmaxf(m, cm);
      float sc = __expf(m - nm);                     // first chunk: exp(-inf)=0
      #pragma unroll
      for (int i = 0; i < 16; ++i) acc[i] *= sc;
      dsum *= sc;
      float ev = (lane < len) ? __expf(lg - nm) : 0.f;
      dsum += ev;
      for (int j = 0; j < len; j += 8) {
        int jj = j + e8;
        float evj = __shfl(ev, jj);
        int svj = __shfl(sv, jj);
        if (jj < len) {
          uint4 U = *(const uint4*)(hvb + (size_t)svj * 128 + l8 * 16);
          floatx2 p;
          p = __builtin_amdgcn_cvt_pk_f32_fp8((int)U.x, false); acc[0] += evj * p[0];  acc[1] += evj * p[1];
          p = __builtin_amdgcn_cvt_pk_f32_fp8((int)U.x, true);  acc[2] += evj * p[0];  acc[3] += evj * p[1];
          p = __builtin_amdgcn_cvt_pk_f32_fp8((int)U.y, false); acc[4] += evj * p[0];  acc[5] += evj * p[1];
          p = __builtin_amdgcn_cvt_pk_f32_fp8((int)U.y, true);  acc[6] += evj * p[0];  acc[7] += evj * p[1];
          p = __builtin_amdgcn_cvt_pk_f32_fp8((int)U.z, false); acc[8] += evj * p[0];  acc[9] += evj * p[1];
          p = __builtin_amdgcn_cvt_pk_f32_fp8((int)U.z, true);  acc[10] += evj * p[0]; acc[11] += evj * p[1];
          p = __builtin_amdgcn_cvt_pk_f32_fp8((int)U.w, false); acc[12] += evj * p[0]; acc[13] += evj * p[1];
          p = __builtin_amdgcn_cvt_pk_f32_fp8((int)U.w, true);  acc[14] += evj * p[0]; acc[15] += evj * p[1];
        }
      }
      m = nm;
    }
  }
  #pragma unroll
  for (int o = 8; o <= 32; o <<= 1)
    #pragma unroll
    for (int i = 0; i < 16; ++i) acc[i] += __shfl_xor(acc[i], o);
  #pragma unroll
  for (int o = 32; o; o >>= 1) dsum += __shfl_xor(dsum, o);
  float r = (dsum > 0.f) ? (1.f / dsum) : 0.f;
  if (lane < 32) {
    int g = lane & 7, p4 = lane >> 3;
    float v0 = acc[p4 * 4 + 0] * r, v1 = acc[p4 * 4 + 1] * r;
    float v2 = acc[p4 * 4 + 2] * r, v3 = acc[p4 * 4 + 3] * r;
    v0 = (v0 > 0.f) ? v0 : expm1f(v0);
    v1 = (v1 > 0.f) ? v1 : expm1f(v1);
    v2 = (v2 > 0.f) ? v2 : expm1f(v2);
    v3 = (v3 > 0.f) ? v3 : expm1f(v3);
    uint2 u;
    u.x = (unsigned)f2bf(v0) | ((unsigned)f2bf(v1) << 16);
    u.y = (unsigned)f2bf(v2) | ((unsigned)f2bf(v3) << 16);
    *(uint2*)(ctxb + (size_t)wid * 128 + g * 16 + p4 * 4) = u;
  }
}

// ---------------------------------------------------------------- fused MLP [MFMA] + BN partials
__global__ __launch_bounds__(256) void k_mlp2(const unsigned short* __restrict__ ctxb,
    const float* __restrict__ nf,
    const unsigned short* __restrict__ w1t, const float* __restrict__ b1,
    const unsigned short* __restrict__ w2t, const float* __restrict__ b2,
    float* __restrict__ out, float* __restrict__ bn_sum, float* __restrict__ bn_sumsq) {
  __shared__ unsigned short xs[64][264];
  __shared__ unsigned short h1s[64][136];
  __shared__ float bns[128], bnq[128];
  int tid = threadIdx.x;
  int m0 = blockIdx.x * 64;
  if (tid < 128) { bns[tid] = 0.f; bnq[tid] = 0.f; }
  #pragma unroll
  for (int e = 0; e < 4; ++e) {
    int idx = tid + 256 * e;                         // uint4 index, 1024 total
    int row = idx >> 4, c8 = idx & 15;
    int m = m0 + row; if (m >= NN) m = NN - 1;
    uint4 v = *(const uint4*)(ctxb + (size_t)m * 128 + c8 * 8);
    *(uint4*)&xs[row][c8 * 8] = v;
  }
  #pragma unroll
  for (int e = 0; e < 8; ++e) {
    int idx = tid + 256 * e;                         // float4 index, 2048 total
    int row = idx >> 5, c4 = idx & 31;
    int m = m0 + row; if (m >= NN) m = NN - 1;
    float4 w = *(const float4*)(nf + (size_t)m * 128 + c4 * 4);
    ushort4 cc;
    cc.x = f2bf(w.x); cc.y = f2bf(w.y); cc.z = f2bf(w.z); cc.w = f2bf(w.w);
    *(ushort4*)&xs[row][128 + c4 * 4] = cc;
  }
  __syncthreads();
  int wid = tid >> 6, lane = tid & 63;
  int wm = wid >> 1, wn = wid & 1;
  int l15 = lane & 15, lg = lane >> 4;
  f32x4 acc[2][4];
  #pragma unroll
  for (int mf = 0; mf < 2; ++mf)
    #pragma unroll
    for (int nf2 = 0; nf2 < 4; ++nf2) acc[mf][nf2] = (f32x4){0.f, 0.f, 0.f, 0.f};
  for (int ks = 0; ks < 8; ++ks) {
    short8v a[2], b[4];
    #pragma unroll
    for (int mf = 0; mf < 2; ++mf)
      a[mf] = *(const short8v*)&xs[wm * 32 + mf * 16 + l15][ks * 32 + lg * 8];
    #pragma unroll
    for (int nf2 = 0; nf2 < 4; ++nf2) {
      int n = wn * 64 + nf2 * 16 + l15;
      b[nf2] = *(const short8v*)(w1t + (size_t)n * 256 + ks * 32 + lg * 8);
    }
    #pragma unroll
    for (int mf = 0; mf < 2; ++mf)
      #pragma unroll
      for (int nf2 = 0; nf2 < 4; ++nf2)
        acc[mf][nf2] = __builtin_amdgcn_mfma_f32_16x16x32_bf16(a[mf], b[nf2], acc[mf][nf2], 0, 0, 0);
  }
  {
    float b1n[4];
    #pragma unroll
    for (int nf2 = 0; nf2 < 4; ++nf2) b1n[nf2] = b1[wn * 64 + nf2 * 16 + l15];
    #pragma unroll
    for (int mf = 0; mf < 2; ++mf)
      #pragma unroll
      for (int nf2 = 0; nf2 < 4; ++nf2)
        #pragma unroll
        for (int r = 0; r < 4; ++r) {
          int row = wm * 32 + mf * 16 + lg * 4 + r;
          int col = wn * 64 + nf2 * 16 + l15;
          float h = fmaxf(acc[mf][nf2][r] + b1n[nf2], 0.f);
          h1s[row][col] = f2bf(h);
        }
  }
  __syncthreads();
  f32x4 acc2[2][4];
  #pragma unroll
  for (int mf = 0; mf < 2; ++mf)
    #pragma unroll
    for (int nf2 = 0; nf2 < 4; ++nf2) acc2[mf][nf2] = (f32x4){0.f, 0.f, 0.f, 0.f};
  for (int ks = 0; ks < 4; ++ks) {
    short8v a[2], b[4];
    #pragma unroll
    for (int mf = 0; mf < 2; ++mf)
      a[mf] = *(const short8v*)&h1s[wm * 32 + mf * 16 + l15][ks * 32 + lg * 8];
    #pragma unroll
    for (int nf2 = 0; nf2 < 4; ++nf2) {
      int n = wn * 64 + nf2 * 16 + l15;
      b[nf2] = *(const short8v*)(w2t + (size_t)n * 128 + ks * 32 + lg * 8);
    }
    #pragma unroll
    for (int mf = 0; mf < 2; ++mf)
      #pragma unroll
      for (int nf2 = 0; nf2 < 4; ++nf2)
        acc2[mf][nf2] = __builtin_amdgcn_mfma_f32_16x16x32_bf16(a[mf], b[nf2], acc2[mf][nf2], 0, 0, 0);
  }
  {
    float b2n[4];
    #pragma unroll
    for (int nf2 = 0; nf2 < 4; ++nf2) b2n[nf2] = b2[wn * 64 + nf2 * 16 + l15];
    float fsum[4] = {0.f, 0.f, 0.f, 0.f}, fsq[4] = {0.f, 0.f, 0.f, 0.f};
    #pragma unroll
    for (int mf = 0; mf < 2; ++mf)
      #pragma unroll
      for (int nf2 = 0; nf2 < 4; ++nf2)
        #pragma unroll
        for (int r = 0; r < 4; ++r) {
          int m = m0 + wm * 32 + mf * 16 + lg * 4 + r;
          int n = wn * 64 + nf2 * 16 + l15;
          float h = fmaxf(acc2[mf][nf2][r] + b2n[nf2], 0.f);
          if (m < NN) {
            out[(size_t)m * 128 + n] = h;
            fsum[nf2] += h;
            fsq[nf2] += h * h;
          }
        }
    #pragma unroll
    for (int nf2 = 0; nf2 < 4; ++nf2) {
      int n = wn * 64 + nf2 * 16 + l15;
      atomicAdd(&bns[n], fsum[nf2]);
      atomicAdd(&bnq[n], fsq[nf2]);
    }
  }
  __syncthreads();
  if (tid < 128) {
    atomicAdd(&bn_sum[tid], bns[tid]);
    atomicAdd(&bn_sumsq[tid], bnq[tid]);
  }
}

// ---------------------------------------------------------------- BN stats + normalize
__global__ __launch_bounds__(128) void k_bnstats(const float* __restrict__ bn_sum,
    const float* __restrict__ bn_sumsq, float* __restrict__ mean,
    float* __restrict__ istd) {
  int t = threadIdx.x;
  float mu = bn_sum[t] / (float)NN;
  float var = bn_sumsq[t] / (float)NN - mu * mu;
  var = fmaxf(var, 0.f);
  mean[t] = mu;
  istd[t] = 1.f / sqrtf(var + 1e-5f);
}

__global__ __launch_bounds__(256) void k_bnorm(float* __restrict__ out,
    const float* __restrict__ mean, const float* __restrict__ istd,
    const float* __restrict__ gamma, const float* __restrict__ beta) {
  int idx = blockIdx.x * 256 + threadIdx.x;
  float4* p = (float4*)out;
  float4 v = p[idx];
  int f = (idx & 31) << 2;
  v.x = gamma[f + 0] * (v.x - mean[f + 0]) * istd[f + 0] + beta[f + 0];
  v.y = gamma[f + 1] * (v.y - mean[f + 1]) * istd[f + 1] + beta[f + 1];
  v.z = gamma[f + 2] * (v.z - mean[f + 2]) * istd[f + 2] + beta[f + 2];
  v.w = gamma[f + 3] * (v.w - mean[f + 3]) * istd[f + 3] + beta[f + 3];
  p[idx] = v;
}

// ----------------------------------------------------------------
extern "C" void kernel_launch(void* const* d_in, const int* in_sizes, int n_in,
                              void* d_out, int out_size, void* d_ws, size_t ws_size,
                              hipStream_t stream) {
  (void)in_sizes; (void)n_in; (void)out_size; (void)ws_size;
  const float* nf    = (const float*)d_in[0];
  const int*   src   = (const int*)d_in[1];
  const int*   dst   = (const int*)d_in[2];
  const float* wed   = (const float*)d_in[3];
  const float* wes   = (const float*)d_in[4];
  const float* be    = (const float*)d_in[5];
  const float* wp    = (const float*)d_in[6];
  const float* bp    = (const float*)d_in[7];
  const float* w1    = (const float*)d_in[8];
  const float* b1    = (const float*)d_in[9];
  const float* w2    = (const float*)d_in[10];
  const float* b2    = (const float*)d_in[11];
  const float* gamma = (const float*)d_in[12];
  const float* beta  = (const float*)d_in[13];
  float* out = (float*)d_out;
  char* ws = (char*)d_ws;

  unsigned char*  hvb  = (unsigned char*)(ws + HVB_OFF);
  unsigned short* ctxb = (unsigned short*)(ws + CTXB_OFF);
  unsigned*       bin  = (unsigned*)(ws + BIN_OFF);
  unsigned short* srcs = (unsigned short*)(ws + SRCS_OFF);
  float* ld    = (float*)(ws + LD_OFF);
  float* ls    = (float*)(ws + LS_OFF);
  int*   start = (int*)(ws + START_OFF);
  int*   cntn  = (int*)(ws + CNTN_OFF);
  unsigned short* w1t = (unsigned short*)(ws + W1T_OFF);
  unsigned short* w2t = (unsigned short*)(ws + W2T_OFF);
  unsigned short* wpt = (unsigned short*)(ws + WPT_OFF);
  int*   bkc   = (int*)(ws + BKC_OFF);
  float* bsum  = (float*)(ws + BSUM_OFF);
  float* bsq   = (float*)(ws + BSQ_OFF);
  float* mean  = (float*)(ws + MEAN_OFF);
  float* istd  = (float*)(ws + ISTD_OFF);

  hipMemsetAsync(ws + ZERO_OFF, 0, ZERO_LEN, stream);

  k_prep_w<<<256, 256, 0, stream>>>(w1, w2, wp, w1t, w2t, wpt);
  k_bin<<<196, 256, 0, stream>>>(src, dst, bkc, bin);
  k_hv2<<<(NN + 63) / 64, 256, 0, stream>>>(nf, wpt, bp, wed, wes, ld, ls, hvb);
  k_bsort<<<NB, 256, 0, stream>>>(bin, bkc, srcs, start, cntn);
  k_agg<<<12500, 256, 0, stream>>>(hvb, ld, ls, be, start, cntn, srcs, ctxb);
  k_mlp2<<<(NN + 63) / 64, 256, 0, stream>>>(ctxb, nf, w1t, b1, w2t, b2, out, bsum, bsq);
  k_bnstats<<<1, 128, 0, stream>>>(bsum, bsq, mean, istd);
  k_bnorm<<<(NN * DD / 4) / 256, 256, 0, stream>>>(out, mean, istd, gamma, beta);
}

// Round 6
// 283.745 us; speedup vs baseline: 2.3274x; 1.0183x over previous
//
#include <hip/hip_runtime.h>
#include <math.h>

#define NN 50000
#define EE 1600000
#define DD 128
#define NB 98            // buckets of 512 nodes
#define SLAB 18432       // slab capacity per bucket (mean 16384, +16 sigma)
#define MROWS 32
#define MGRID 1563       // (NN + MROWS - 1) / MROWS

typedef __attribute__((ext_vector_type(8))) short short8v;
typedef __attribute__((ext_vector_type(4))) float f32x4;
typedef __attribute__((ext_vector_type(2))) float floatx2;

// workspace layout (bytes)
#define HVB_OFF     0            // [NN*128] fp8 = 6,400,000
#define CTXB_OFF    6400000      // [NN*128] bf16 = 12,800,000
#define BIN_OFF     19200000     // [NB*SLAB] u32 = 7,225,344
#define SRCS_OFF    26425344     // [NB*SLAB] u16 = 3,612,672
#define LD_OFF      30038016     // [NN] f32
#define LS_OFF      30238016     // [NN] f32
#define START_OFF   30438016     // [NN] i32
#define CNTN_OFF    30638016     // [NN] i32
#define W1T_OFF     30838016     // [128*256] bf16
#define W2T_OFF     30903552     // [128*128] bf16
#define WPT_OFF     30936320     // [128*128] bf16
#define BKC_OFF     30969088     // [128] i32 (zeroed)
#define MEAN_OFF    30969600     // [128] f32
#define ISTD_OFF    30970112     // [128] f32
#define PBN_OFF     30971648     // [MGRID*128] f32 = 800,256
#define PBQ_OFF     31771904     // [MGRID*128] f32 = 800,256 (ends 32,572,160)
#define ZERO_OFF    BKC_OFF
#define ZERO_LEN    512          // BKC only

__device__ __forceinline__ unsigned short f2bf(float f) {
  union { float f; unsigned u; } v; v.f = f;
  unsigned r = v.u + 0x7FFFu + ((v.u >> 16) & 1u);   // round-to-nearest-even
  return (unsigned short)(r >> 16);
}

// ---------------------------------------------------------------- prep: weight transposes (to [n][k] bf16)
__global__ __launch_bounds__(256) void k_prep_w(const float* __restrict__ w1,
    const float* __restrict__ w2, const float* __restrict__ wp,
    unsigned short* __restrict__ w1t, unsigned short* __restrict__ w2t,
    unsigned short* __restrict__ wpt) {
  int t = blockIdx.x * 256 + threadIdx.x;            // 0..65535
  if (t < 32768) {
    int n = t & 127, k = t >> 7;                     // k 0..255
    w1t[n * 256 + k] = f2bf(w1[(size_t)k * 128 + n]);
  } else if (t < 49152) {
    int i = t - 32768; int n = i & 127, k = i >> 7;
    w2t[n * 128 + k] = f2bf(w2[(size_t)k * 128 + n]);
  } else {
    int i = t - 49152; int n = i & 127, k = i >> 7;
    wpt[n * 128 + k] = f2bf(wp[(size_t)k * 128 + n]);
  }
}

// ---------------------------------------------------------------- hv (fp8) + ld/ls, fused  [MFMA]
__global__ __launch_bounds__(256) void k_hv2(const float* __restrict__ nf,
    const unsigned short* __restrict__ wpt, const float* __restrict__ bp,
    const float* __restrict__ wed, const float* __restrict__ wes,
    float* __restrict__ ld, float* __restrict__ ls,
    unsigned char* __restrict__ hvb) {
  __shared__ unsigned short xs[64][136];
  int tid = threadIdx.x;
  int m0 = blockIdx.x * 64;
  int c4 = tid & 31;
  float4 wdv = *(const float4*)(wed + c4 * 4);
  float4 wsv = *(const float4*)(wes + c4 * 4);
  #pragma unroll
  for (int e = 0; e < 8; ++e) {
    int idx = tid + 256 * e;                         // float4 index, 2048 total
    int row = idx >> 5;
    int m = m0 + row;
    int mc = (m < NN) ? m : (NN - 1);
    float4 v = *(const float4*)(nf + (size_t)mc * 128 + c4 * 4);
    ushort4 bb;
    bb.x = f2bf(v.x); bb.y = f2bf(v.y); bb.z = f2bf(v.z); bb.w = f2bf(v.w);
    *(ushort4*)&xs[row][c4 * 4] = bb;
    float pa = v.x * wdv.x + v.y * wdv.y + v.z * wdv.z + v.w * wdv.w;
    float pb = v.x * wsv.x + v.y * wsv.y + v.z * wsv.z + v.w * wsv.w;
    #pragma unroll
    for (int o = 16; o; o >>= 1) { pa += __shfl_xor(pa, o); pb += __shfl_xor(pb, o); }
    if (c4 == 0 && m < NN) { ld[m] = pa; ls[m] = pb; }
  }
  __syncthreads();
  int wid = tid >> 6, lane = tid & 63;
  int wm = wid >> 1, wn = wid & 1;
  int l15 = lane & 15, lg = lane >> 4;
  f32x4 acc[4][2];                                   // [n-frag][m-frag]
  #pragma unroll
  for (int nf2 = 0; nf2 < 4; ++nf2)
    #pragma unroll
    for (int mf = 0; mf < 2; ++mf) acc[nf2][mf] = (f32x4){0.f, 0.f, 0.f, 0.f};
  for (int ks = 0; ks < 4; ++ks) {
    short8v aw[4], bx[2];
    #pragma unroll
    for (int nf2 = 0; nf2 < 4; ++nf2) {
      int n = wn * 64 + nf2 * 16 + l15;
      aw[nf2] = *(const short8v*)(wpt + (size_t)n * 128 + ks * 32 + lg * 8);
    }
    #pragma unroll
    for (int mf = 0; mf < 2; ++mf)
      bx[mf] = *(const short8v*)&xs[wm * 32 + mf * 16 + l15][ks * 32 + lg * 8];
    #pragma unroll
    for (int nf2 = 0; nf2 < 4; ++nf2)
      #pragma unroll
      for (int mf = 0; mf < 2; ++mf)
        acc[nf2][mf] = __builtin_amdgcn_mfma_f32_16x16x32_bf16(aw[nf2], bx[mf], acc[nf2][mf], 0, 0, 0);
  }
  #pragma unroll
  for (int nf2 = 0; nf2 < 4; ++nf2) {
    float4 bp4 = *(const float4*)(bp + wn * 64 + nf2 * 16 + lg * 4);
    #pragma unroll
    for (int mf = 0; mf < 2; ++mf) {
      int m = m0 + wm * 32 + mf * 16 + l15;
      if (m < NN) {
        int w = __builtin_amdgcn_cvt_pk_fp8_f32(acc[nf2][mf][0] + bp4.x,
                                                acc[nf2][mf][1] + bp4.y, 0, false);
        w = __builtin_amdgcn_cvt_pk_fp8_f32(acc[nf2][mf][2] + bp4.z,
                                            acc[nf2][mf][3] + bp4.w, w, true);
        *(int*)(hvb + (size_t)m * 128 + wn * 64 + nf2 * 16 + lg * 4) = w;
      }
    }
  }
}

// ---------------------------------------------------------------- sort S1: bin edges (packed dst<<16|src) into bucket slabs
__global__ __launch_bounds__(256) void k_bin(const int* __restrict__ src,
    const int* __restrict__ dst, int* __restrict__ bkc,
    unsigned* __restrict__ bin) {
  __shared__ unsigned slot[8192];
  __shared__ int hist[128], sc[128], loff[128], lcur[128], gbase[128];
  int tid = threadIdx.x;
  int tbase = blockIdx.x * 8192;
  int tlen = min(8192, EE - tbase);
  unsigned pk[32];
  if (tid < 128) hist[tid] = 0;
  __syncthreads();
  #pragma unroll
  for (int k = 0; k < 32; ++k) {
    int i = k * 256 + tid;
    if (i < tlen) {
      int e = tbase + i;
      pk[k] = ((unsigned)dst[e] << 16) | (unsigned)src[e];
      atomicAdd(&hist[pk[k] >> 25], 1);
    }
  }
  __syncthreads();
  if (tid < 128) sc[tid] = hist[tid];
  __syncthreads();
  for (int off = 1; off < 128; off <<= 1) {
    int v = 0;
    if (tid < 128) v = sc[tid] + ((tid >= off) ? sc[tid - off] : 0);
    __syncthreads();
    if (tid < 128) sc[tid] = v;
    __syncthreads();
  }
  if (tid < 128) { loff[tid] = sc[tid] - hist[tid]; lcur[tid] = sc[tid] - hist[tid]; }
  __syncthreads();
  #pragma unroll
  for (int k = 0; k < 32; ++k) {
    int i = k * 256 + tid;
    if (i < tlen) {
      int r = atomicAdd(&lcur[pk[k] >> 25], 1);
      slot[r] = pk[k];
    }
  }
  __syncthreads();
  if (tid < 128) gbase[tid] = hist[tid] ? atomicAdd(&bkc[tid], hist[tid]) : 0;
  __syncthreads();
  #pragma unroll
  for (int k = 0; k < 32; ++k) {
    int i = k * 256 + tid;
    if (i < tlen) {
      unsigned p = slot[i];
      int b = p >> 25;
      bin[(size_t)b * SLAB + gbase[b] + (i - loff[b])] = p;
    }
  }
}

// ---------------------------------------------------------------- sort S2: per-bucket node sort, emit srcs + start/count
__global__ __launch_bounds__(256) void k_bsort(const unsigned* __restrict__ bin,
    const int* __restrict__ bkc, unsigned short* __restrict__ srcs,
    int* __restrict__ start, int* __restrict__ cntn) {
  __shared__ unsigned eL[SLAB];
  __shared__ unsigned short outL[SLAB];
  __shared__ int hist[512], scA[512], cur[512];
  int tid = threadIdx.x;
  int b = blockIdx.x;
  int base = b * SLAB;
  int cnt = bkc[b];
  int node0 = b << 9;
  int nnb = min(512, NN - node0);
  for (int i = tid; i < 512; i += 256) hist[i] = 0;
  __syncthreads();
  for (int i = tid; i < cnt; i += 256) {
    unsigned p = bin[base + i];
    eL[i] = p;
    atomicAdd(&hist[(p >> 16) & 511], 1);
  }
  __syncthreads();
  for (int i = tid; i < 512; i += 256) scA[i] = hist[i];
  __syncthreads();
  for (int off = 1; off < 512; off <<= 1) {
    int v0 = scA[tid] + ((tid >= off) ? scA[tid - off] : 0);
    int i1 = tid + 256;
    int v1 = scA[i1] + ((i1 >= off) ? scA[i1 - off] : 0);
    __syncthreads();
    scA[tid] = v0; scA[i1] = v1;
    __syncthreads();
  }
  for (int i = tid; i < 512; i += 256) {
    int ex = scA[i] - hist[i];
    cur[i] = ex;
    if (i < nnb) { start[node0 + i] = base + ex; cntn[node0 + i] = hist[i]; }
  }
  __syncthreads();
  for (int i = tid; i < cnt; i += 256) {
    unsigned p = eL[i];
    int r = atomicAdd(&cur[(p >> 16) & 511], 1);
    outL[r] = (unsigned short)(p & 0xFFFFu);
  }
  __syncthreads();
  for (int i = tid; i < cnt; i += 256) srcs[base + i] = outL[i];
}

// ---------------------------------------------------------------- edge softmax + aggregate + ELU -> bf16 context
__global__ __launch_bounds__(256) void k_agg(const unsigned char* __restrict__ hvb,
    const float* __restrict__ ld, const float* __restrict__ ls,
    const float* __restrict__ be_p, const int* __restrict__ start,
    const int* __restrict__ cntn, const unsigned short* __restrict__ srcs,
    unsigned short* __restrict__ ctxb) {
  int wid = (blockIdx.x * 256 + threadIdx.x) >> 6;
  int lane = threadIdx.x & 63;
  if (wid >= NN) return;
  int cnt = cntn[wid];
  int l8 = lane & 7, e8 = lane >> 3;
  float acc[16];
  #pragma unroll
  for (int i = 0; i < 16; ++i) acc[i] = 0.f;
  float m = -INFINITY, dsum = 0.f;
  if (cnt > 0) {
    int s = start[wid];
    float base = ld[wid] + be_p[0];
    for (int c0 = 0; c0 < cnt; c0 += 64) {
      int len = min(64, cnt - c0);
      float lg = -INFINITY;
      int sv = 0;
      if (lane < len) {
        sv = srcs[s + c0 + lane];
        float l = base + ls[sv];
        lg = (l >= 0.f) ? l : 0.01f * l;
      }
      float cm = lg;
      #pragma unroll
      for (int o = 32; o; o >>= 1) cm = fmaxf(cm, __shfl_xor(cm, o));
      float nm = fmaxf(m, cm);
      float sc = __expf(m - nm);                     // first chunk: exp(-inf)=0
      #pragma unroll
      for (int i = 0; i < 16; ++i) acc[i] *= sc;
      dsum *= sc;
      float ev = (lane < len) ? __expf(lg - nm) : 0.f;
      dsum += ev;
      for (int j = 0; j < len; j += 8) {
        int jj = j + e8;
        float evj = __shfl(ev, jj);
        int svj = __shfl(sv, jj);
        if (jj < len) {
          uint4 U = *(const uint4*)(hvb + (size_t)svj * 128 + l8 * 16);
          floatx2 p;
          p = __builtin_amdgcn_cvt_pk_f32_fp8((int)U.x, false); acc[0] += evj * p[0];  acc[1] += evj * p[1];
          p = __builtin_amdgcn_cvt_pk_f32_fp8((int)U.x, true);  acc[2] += evj * p[0];  acc[3] += evj * p[1];
          p = __builtin_amdgcn_cvt_pk_f32_fp8((int)U.y, false); acc[4] += evj * p[0];  acc[5] += evj * p[1];
          p = __builtin_amdgcn_cvt_pk_f32_fp8((int)U.y, true);  acc[6] += evj * p[0];  acc[7] += evj * p[1];
          p = __builtin_amdgcn_cvt_pk_f32_fp8((int)U.z, false); acc[8] += evj * p[0];  acc[9] += evj * p[1];
          p = __builtin_amdgcn_cvt_pk_f32_fp8((int)U.z, true);  acc[10] += evj * p[0]; acc[11] += evj * p[1];
          p = __builtin_amdgcn_cvt_pk_f32_fp8((int)U.w, false); acc[12] += evj * p[0]; acc[13] += evj * p[1];
          p = __builtin_amdgcn_cvt_pk_f32_fp8((int)U.w, true);  acc[14] += evj * p[0]; acc[15] += evj * p[1];
        }
      }
      m = nm;
    }
  }
  #pragma unroll
  for (int o = 8; o <= 32; o <<= 1)
    #pragma unroll
    for (int i = 0; i < 16; ++i) acc[i] += __shfl_xor(acc[i], o);
  #pragma unroll
  for (int o = 32; o; o >>= 1) dsum += __shfl_xor(dsum, o);
  float r = (dsum > 0.f) ? (1.f / dsum) : 0.f;
  if (lane < 32) {
    int g = lane & 7, p4 = lane >> 3;
    float v0 = acc[p4 * 4 + 0] * r, v1 = acc[p4 * 4 + 1] * r;
    float v2 = acc[p4 * 4 + 2] * r, v3 = acc[p4 * 4 + 3] * r;
    v0 = (v0 > 0.f) ? v0 : expm1f(v0);
    v1 = (v1 > 0.f) ? v1 : expm1f(v1);
    v2 = (v2 > 0.f) ? v2 : expm1f(v2);
    v3 = (v3 > 0.f) ? v3 : expm1f(v3);
    uint2 u;
    u.x = (unsigned)f2bf(v0) | ((unsigned)f2bf(v1) << 16);
    u.y = (unsigned)f2bf(v2) | ((unsigned)f2bf(v3) << 16);
    *(uint2*)(ctxb + (size_t)wid * 128 + g * 16 + p4 * 4) = u;
  }
}

// ---------------------------------------------------------------- fused MLP [MFMA], 32-row tiles, no global atomics
__global__ __launch_bounds__(256) void k_mlp2(const unsigned short* __restrict__ ctxb,
    const float* __restrict__ nf,
    const unsigned short* __restrict__ w1t, const float* __restrict__ b1,
    const unsigned short* __restrict__ w2t, const float* __restrict__ b2,
    float* __restrict__ out, float* __restrict__ pbn, float* __restrict__ pbq) {
  __shared__ unsigned short xs[MROWS][264];          // [m][k] bf16 (ctx | nf)
  __shared__ unsigned short h1s[MROWS][136];         // [m][n] bf16
  __shared__ float bns[128], bnq[128];
  int tid = threadIdx.x;
  int m0 = blockIdx.x * MROWS;
  if (tid < 128) { bns[tid] = 0.f; bnq[tid] = 0.f; }
  // stage ctx (bf16): 32 rows x 16 uint4 = 512 -> 2/thread
  #pragma unroll
  for (int e = 0; e < 2; ++e) {
    int idx = tid + 256 * e;
    int row = idx >> 4, c8 = idx & 15;
    int m = m0 + row; if (m >= NN) m = NN - 1;
    uint4 v = *(const uint4*)(ctxb + (size_t)m * 128 + c8 * 8);
    *(uint4*)&xs[row][c8 * 8] = v;
  }
  // stage nf (f32->bf16): 32 rows x 32 float4 = 1024 -> 4/thread
  #pragma unroll
  for (int e = 0; e < 4; ++e) {
    int idx = tid + 256 * e;
    int row = idx >> 5, c4 = idx & 31;
    int m = m0 + row; if (m >= NN) m = NN - 1;
    float4 w = *(const float4*)(nf + (size_t)m * 128 + c4 * 4);
    ushort4 cc;
    cc.x = f2bf(w.x); cc.y = f2bf(w.y); cc.z = f2bf(w.z); cc.w = f2bf(w.w);
    *(ushort4*)&xs[row][128 + c4 * 4] = cc;
  }
  __syncthreads();
  int wid = tid >> 6, lane = tid & 63;
  int wm = wid >> 1, wn = wid & 1;                   // wave tile: 16 rows x 64 cols
  int l15 = lane & 15, lg = lane >> 4;
  // ---- layer 1: [32x256] @ [256x128]; D: m=lg*4+r, n=l15
  f32x4 acc[4];
  #pragma unroll
  for (int nf2 = 0; nf2 < 4; ++nf2) acc[nf2] = (f32x4){0.f, 0.f, 0.f, 0.f};
  for (int ks = 0; ks < 8; ++ks) {
    short8v a = *(const short8v*)&xs[wm * 16 + l15][ks * 32 + lg * 8];
    #pragma unroll
    for (int nf2 = 0; nf2 < 4; ++nf2) {
      int n = wn * 64 + nf2 * 16 + l15;
      short8v b = *(const short8v*)(w1t + (size_t)n * 256 + ks * 32 + lg * 8);
      acc[nf2] = __builtin_amdgcn_mfma_f32_16x16x32_bf16(a, b, acc[nf2], 0, 0, 0);
    }
  }
  {
    float b1n[4];
    #pragma unroll
    for (int nf2 = 0; nf2 < 4; ++nf2) b1n[nf2] = b1[wn * 64 + nf2 * 16 + l15];
    #pragma unroll
    for (int nf2 = 0; nf2 < 4; ++nf2)
      #pragma unroll
      for (int r = 0; r < 4; ++r) {
        int row = wm * 16 + lg * 4 + r;
        int col = wn * 64 + nf2 * 16 + l15;
        h1s[row][col] = f2bf(fmaxf(acc[nf2][r] + b1n[nf2], 0.f));
      }
  }
  __syncthreads();
  // ---- layer 2 swapped: A = w2 rows (n), B = h1 rows (m); D: n=lg*4+r, m=l15
  f32x4 acc2[4];
  #pragma unroll
  for (int nf2 = 0; nf2 < 4; ++nf2) acc2[nf2] = (f32x4){0.f, 0.f, 0.f, 0.f};
  for (int ks = 0; ks < 4; ++ks) {
    short8v bh = *(const short8v*)&h1s[wm * 16 + l15][ks * 32 + lg * 8];
    #pragma unroll
    for (int nf2 = 0; nf2 < 4; ++nf2) {
      int n = wn * 64 + nf2 * 16 + l15;
      short8v aw = *(const short8v*)(w2t + (size_t)n * 128 + ks * 32 + lg * 8);
      acc2[nf2] = __builtin_amdgcn_mfma_f32_16x16x32_bf16(aw, bh, acc2[nf2], 0, 0, 0);
    }
  }
  // epilogue: relu(h2+b2) -> float4 store; BN partials via l15-butterfly + LDS
  {
    int m = m0 + wm * 16 + l15;
    bool valid = (m < NN);
    float hs[4][4], hq[4][4];
    #pragma unroll
    for (int nf2 = 0; nf2 < 4; ++nf2) {
      int f0 = wn * 64 + nf2 * 16 + lg * 4;
      float4 b24 = *(const float4*)(b2 + f0);
      float h0 = fmaxf(acc2[nf2][0] + b24.x, 0.f);
      float h1v = fmaxf(acc2[nf2][1] + b24.y, 0.f);
      float h2v = fmaxf(acc2[nf2][2] + b24.z, 0.f);
      float h3v = fmaxf(acc2[nf2][3] + b24.w, 0.f);
      if (valid) {
        float4 o = make_float4(h0, h1v, h2v, h3v);
        *(float4*)(out + (size_t)m * 128 + f0) = o;
      } else { h0 = h1v = h2v = h3v = 0.f; }
      hs[nf2][0] = h0; hs[nf2][1] = h1v; hs[nf2][2] = h2v; hs[nf2][3] = h3v;
      hq[nf2][0] = h0 * h0; hq[nf2][1] = h1v * h1v;
      hq[nf2][2] = h2v * h2v; hq[nf2][3] = h3v * h3v;
    }
    #pragma unroll
    for (int o = 1; o <= 8; o <<= 1)
      #pragma unroll
      for (int nf2 = 0; nf2 < 4; ++nf2)
        #pragma unroll
        for (int r = 0; r < 4; ++r) {
          hs[nf2][r] += __shfl_xor(hs[nf2][r], o);
          hq[nf2][r] += __shfl_xor(hq[nf2][r], o);
        }
    if (l15 == 0) {
      #pragma unroll
      for (int nf2 = 0; nf2 < 4; ++nf2) {
        int f0 = wn * 64 + nf2 * 16 + lg * 4;
        #pragma unroll
        for (int r = 0; r < 4; ++r) {
          atomicAdd(&bns[f0 + r], hs[nf2][r]);
          atomicAdd(&bnq[f0 + r], hq[nf2][r]);
        }
      }
    }
  }
  __syncthreads();
  if (tid < 128) {
    pbn[(size_t)blockIdx.x * 128 + tid] = bns[tid];
    pbq[(size_t)blockIdx.x * 128 + tid] = bnq[tid];
  }
}

// ---------------------------------------------------------------- BN stats: reduce per-block partials (one block per feature)
__global__ __launch_bounds__(256) void k_bnstats2(const float* __restrict__ pbn,
    const float* __restrict__ pbq, float* __restrict__ mean,
    float* __restrict__ istd) {
  int f = blockIdx.x;
  float s = 0.f, q = 0.f;
  for (int b = threadIdx.x; b < MGRID; b += 256) {
    s += pbn[(size_t)b * 128 + f];
    q += pbq[(size_t)b * 128 + f];
  }
  #pragma unroll
  for (int o = 32; o; o >>= 1) { s += __shfl_xor(s, o); q += __shfl_xor(q, o); }
  __shared__ float ss[4], sq[4];
  int wid = threadIdx.x >> 6, lane = threadIdx.x & 63;
  if (lane == 0) { ss[wid] = s; sq[wid] = q; }
  __syncthreads();
  if (threadIdx.x == 0) {
    float S = ss[0] + ss[1] + ss[2] + ss[3];
    float Q = sq[0] + sq[1] + sq[2] + sq[3];
    float mu = S / (float)NN;
    float var = fmaxf(Q / (float)NN - mu * mu, 0.f);
    mean[f] = mu;
    istd[f] = 1.f / sqrtf(var + 1e-5f);
  }
}

__global__ __launch_bounds__(256) void k_bnorm(float* __restrict__ out,
    const float* __restrict__ mean, const float* __restrict__ istd,
    const float* __restrict__ gamma, const float* __restrict__ beta) {
  int idx = blockIdx.x * 256 + threadIdx.x;
  float4* p = (float4*)out;
  float4 v = p[idx];
  int f = (idx & 31) << 2;
  v.x = gamma[f + 0] * (v.x - mean[f + 0]) * istd[f + 0] + beta[f + 0];
  v.y = gamma[f + 1] * (v.y - mean[f + 1]) * istd[f + 1] + beta[f + 1];
  v.z = gamma[f + 2] * (v.z - mean[f + 2]) * istd[f + 2] + beta[f + 2];
  v.w = gamma[f + 3] * (v.w - mean[f + 3]) * istd[f + 3] + beta[f + 3];
  p[idx] = v;
}

// ----------------------------------------------------------------
extern "C" void kernel_launch(void* const* d_in, const int* in_sizes, int n_in,
                              void* d_out, int out_size, void* d_ws, size_t ws_size,
                              hipStream_t stream) {
  (void)in_sizes; (void)n_in; (void)out_size; (void)ws_size;
  const float* nf    = (const float*)d_in[0];
  const int*   src   = (const int*)d_in[1];
  const int*   dst   = (const int*)d_in[2];
  const float* wed   = (const float*)d_in[3];
  const float* wes   = (const float*)d_in[4];
  const float* be    = (const float*)d_in[5];
  const float* wp    = (const float*)d_in[6];
  const float* bp    = (const float*)d_in[7];
  const float* w1    = (const float*)d_in[8];
  const float* b1    = (const float*)d_in[9];
  const float* w2    = (const float*)d_in[10];
  const float* b2    = (const float*)d_in[11];
  const float* gamma = (const float*)d_in[12];
  const float* beta  = (const float*)d_in[13];
  float* out = (float*)d_out;
  char* ws = (char*)d_ws;

  unsigned char*  hvb  = (unsigned char*)(ws + HVB_OFF);
  unsigned short* ctxb = (unsigned short*)(ws + CTXB_OFF);
  unsigned*       bin  = (unsigned*)(ws + BIN_OFF);
  unsigned short* srcs = (unsigned short*)(ws + SRCS_OFF);
  float* ld    = (float*)(ws + LD_OFF);
  float* ls    = (float*)(ws + LS_OFF);
  int*   start = (int*)(ws + START_OFF);
  int*   cntn  = (int*)(ws + CNTN_OFF);
  unsigned short* w1t = (unsigned short*)(ws + W1T_OFF);
  unsigned short* w2t = (unsigned short*)(ws + W2T_OFF);
  unsigned short* wpt = (unsigned short*)(ws + WPT_OFF);
  int*   bkc   = (int*)(ws + BKC_OFF);
  float* mean  = (float*)(ws + MEAN_OFF);
  float* istd  = (float*)(ws + ISTD_OFF);
  float* pbn   = (float*)(ws + PBN_OFF);
  float* pbq   = (float*)(ws + PBQ_OFF);

  hipMemsetAsync(ws + ZERO_OFF, 0, ZERO_LEN, stream);

  k_prep_w<<<256, 256, 0, stream>>>(w1, w2, wp, w1t, w2t, wpt);
  k_bin<<<196, 256, 0, stream>>>(src, dst, bkc, bin);
  k_hv2<<<(NN + 63) / 64, 256, 0, stream>>>(nf, wpt, bp, wed, wes, ld, ls, hvb);
  k_bsort<<<NB, 256, 0, stream>>>(bin, bkc, srcs, start, cntn);
  k_agg<<<12500, 256, 0, stream>>>(hvb, ld, ls, be, start, cntn, srcs, ctxb);
  k_mlp2<<<MGRID, 256, 0, stream>>>(ctxb, nf, w1t, b1, w2t, b2, out, pbn, pbq);
  k_bnstats2<<<128, 256, 0, stream>>>(pbn, pbq, mean, istd);
  k_bnorm<<<(NN * DD / 4) / 256, 256, 0, stream>>>(out, mean, istd, gamma, beta);
}

// Round 9
// 265.679 us; speedup vs baseline: 2.4857x; 1.0680x over previous
//
#include <hip/hip_runtime.h>
#include <math.h>

#define NN 50000
#define EE 1600000
#define DD 128
#define NB 391           // buckets of 128 nodes
#define SLAB 5120        // slab capacity per bucket (mean 4096, +16 sigma)
#define MROWS 32
#define MGRID 1563       // (NN + MROWS - 1) / MROWS

typedef __attribute__((ext_vector_type(8))) short short8v;
typedef __attribute__((ext_vector_type(4))) float f32x4;
typedef __attribute__((ext_vector_type(2))) float floatx2;

// workspace layout (bytes)
#define HVB_OFF     0            // [NN*128] fp8 = 6,400,000
#define CTXB_OFF    6400000      // [NN*128] bf16 = 12,800,000
#define BIN_OFF     19200000     // [NB*SLAB] u32 = 8,007,680 (dead after k_bsort)
#define PBN_OFF     19200000     //   overlay: [MGRID*128] f32 = 800,256
#define PBQ_OFF     20000256     //   overlay: [MGRID*128] f32 = 800,256
#define SRCS_OFF    27207680     // [NB*SLAB] u16 = 4,003,840
#define LD_OFF      31211520     // [NN] f32
#define LS_OFF      31411520     // [NN] f32
#define START_OFF   31611520     // [NN] i32
#define CNTN_OFF    31811520     // [NN] i32
#define W1T_OFF     32011520     // [128*256] bf16
#define W2T_OFF     32077056     // [128*128] bf16
#define WPT_OFF     32109824     // [128*128] bf16
#define BKC_OFF     32142592     // [512] i32 (zeroed)
#define MEAN_OFF    32144640     // [128] f32
#define ISTD_OFF    32145152     // [128] f32  (ends 32,145,664)
#define ZERO_OFF    BKC_OFF
#define ZERO_LEN    2048         // BKC only

__device__ __forceinline__ unsigned short f2bf(float f) {
  union { float f; unsigned u; } v; v.f = f;
  unsigned r = v.u + 0x7FFFu + ((v.u >> 16) & 1u);   // round-to-nearest-even
  return (unsigned short)(r >> 16);
}

// ---------------------------------------------------------------- prep: weight transposes (to [n][k] bf16)
__global__ __launch_bounds__(256) void k_prep_w(const float* __restrict__ w1,
    const float* __restrict__ w2, const float* __restrict__ wp,
    unsigned short* __restrict__ w1t, unsigned short* __restrict__ w2t,
    unsigned short* __restrict__ wpt) {
  int t = blockIdx.x * 256 + threadIdx.x;            // 0..65535
  if (t < 32768) {
    int n = t & 127, k = t >> 7;                     // k 0..255
    w1t[n * 256 + k] = f2bf(w1[(size_t)k * 128 + n]);
  } else if (t < 49152) {
    int i = t - 32768; int n = i & 127, k = i >> 7;
    w2t[n * 128 + k] = f2bf(w2[(size_t)k * 128 + n]);
  } else {
    int i = t - 49152; int n = i & 127, k = i >> 7;
    wpt[n * 128 + k] = f2bf(wp[(size_t)k * 128 + n]);
  }
}

// ---------------------------------------------------------------- hv (fp8) + ld/ls, fused  [MFMA]
__global__ __launch_bounds__(256) void k_hv2(const float* __restrict__ nf,
    const unsigned short* __restrict__ wpt, const float* __restrict__ bp,
    const float* __restrict__ wed, const float* __restrict__ wes,
    float* __restrict__ ld, float* __restrict__ ls,
    unsigned char* __restrict__ hvb) {
  __shared__ unsigned short xs[64][136];
  int tid = threadIdx.x;
  int m0 = blockIdx.x * 64;
  int c4 = tid & 31;
  float4 wdv = *(const float4*)(wed + c4 * 4);
  float4 wsv = *(const float4*)(wes + c4 * 4);
  #pragma unroll
  for (int e = 0; e < 8; ++e) {
    int idx = tid + 256 * e;                         // float4 index, 2048 total
    int row = idx >> 5;
    int m = m0 + row;
    int mc = (m < NN) ? m : (NN - 1);
    float4 v = *(const float4*)(nf + (size_t)mc * 128 + c4 * 4);
    ushort4 bb;
    bb.x = f2bf(v.x); bb.y = f2bf(v.y); bb.z = f2bf(v.z); bb.w = f2bf(v.w);
    *(ushort4*)&xs[row][c4 * 4] = bb;
    float pa = v.x * wdv.x + v.y * wdv.y + v.z * wdv.z + v.w * wdv.w;
    float pb = v.x * wsv.x + v.y * wsv.y + v.z * wsv.z + v.w * wsv.w;
    #pragma unroll
    for (int o = 16; o; o >>= 1) { pa += __shfl_xor(pa, o); pb += __shfl_xor(pb, o); }
    if (c4 == 0 && m < NN) { ld[m] = pa; ls[m] = pb; }
  }
  __syncthreads();
  int wid = tid >> 6, lane = tid & 63;
  int wm = wid >> 1, wn = wid & 1;
  int l15 = lane & 15, lg = lane >> 4;
  f32x4 acc[4][2];                                   // [n-frag][m-frag]
  #pragma unroll
  for (int nf2 = 0; nf2 < 4; ++nf2)
    #pragma unroll
    for (int mf = 0; mf < 2; ++mf) acc[nf2][mf] = (f32x4){0.f, 0.f, 0.f, 0.f};
  for (int ks = 0; ks < 4; ++ks) {
    short8v aw[4], bx[2];
    #pragma unroll
    for (int nf2 = 0; nf2 < 4; ++nf2) {
      int n = wn * 64 + nf2 * 16 + l15;
      aw[nf2] = *(const short8v*)(wpt + (size_t)n * 128 + ks * 32 + lg * 8);
    }
    #pragma unroll
    for (int mf = 0; mf < 2; ++mf)
      bx[mf] = *(const short8v*)&xs[wm * 32 + mf * 16 + l15][ks * 32 + lg * 8];
    #pragma unroll
    for (int nf2 = 0; nf2 < 4; ++nf2)
      #pragma unroll
      for (int mf = 0; mf < 2; ++mf)
        acc[nf2][mf] = __builtin_amdgcn_mfma_f32_16x16x32_bf16(aw[nf2], bx[mf], acc[nf2][mf], 0, 0, 0);
  }
  #pragma unroll
  for (int nf2 = 0; nf2 < 4; ++nf2) {
    float4 bp4 = *(const float4*)(bp + wn * 64 + nf2 * 16 + lg * 4);
    #pragma unroll
    for (int mf = 0; mf < 2; ++mf) {
      int m = m0 + wm * 32 + mf * 16 + l15;
      if (m < NN) {
        int w = __builtin_amdgcn_cvt_pk_fp8_f32(acc[nf2][mf][0] + bp4.x,
                                                acc[nf2][mf][1] + bp4.y, 0, false);
        w = __builtin_amdgcn_cvt_pk_fp8_f32(acc[nf2][mf][2] + bp4.z,
                                            acc[nf2][mf][3] + bp4.w, w, true);
        *(int*)(hvb + (size_t)m * 128 + wn * 64 + nf2 * 16 + lg * 4) = w;
      }
    }
  }
}

// ---------------------------------------------------------------- sort S1: bin edges (packed dst<<16|src) into bucket slabs
__global__ __launch_bounds__(256) void k_bin(const int* __restrict__ src,
    const int* __restrict__ dst, int* __restrict__ bkc,
    unsigned* __restrict__ bin) {
  __shared__ unsigned slot[8192];
  __shared__ int hist[512], sc[512], loff[512], lcur[512], gbase[512];
  int tid = threadIdx.x;
  int tbase = blockIdx.x * 8192;
  int tlen = min(8192, EE - tbase);
  unsigned pk[32];
  for (int i = tid; i < 512; i += 256) hist[i] = 0;
  __syncthreads();
  #pragma unroll
  for (int k = 0; k < 32; ++k) {
    int i = k * 256 + tid;
    if (i < tlen) {
      int e = tbase + i;
      pk[k] = ((unsigned)dst[e] << 16) | (unsigned)src[e];
      atomicAdd(&hist[pk[k] >> 23], 1);
    }
  }
  __syncthreads();
  for (int i = tid; i < 512; i += 256) sc[i] = hist[i];
  __syncthreads();
  for (int off = 1; off < 512; off <<= 1) {
    int v0 = sc[tid] + ((tid >= off) ? sc[tid - off] : 0);
    int i1 = tid + 256;
    int v1 = sc[i1] + ((i1 >= off) ? sc[i1 - off] : 0);
    __syncthreads();
    sc[tid] = v0; sc[i1] = v1;
    __syncthreads();
  }
  for (int i = tid; i < 512; i += 256) { loff[i] = sc[i] - hist[i]; lcur[i] = sc[i] - hist[i]; }
  __syncthreads();
  #pragma unroll
  for (int k = 0; k < 32; ++k) {
    int i = k * 256 + tid;
    if (i < tlen) {
      int r = atomicAdd(&lcur[pk[k] >> 23], 1);
      slot[r] = pk[k];
    }
  }
  __syncthreads();
  for (int i = tid; i < 512; i += 256) gbase[i] = hist[i] ? atomicAdd(&bkc[i], hist[i]) : 0;
  __syncthreads();
  #pragma unroll
  for (int k = 0; k < 32; ++k) {
    int i = k * 256 + tid;
    if (i < tlen) {
      unsigned p = slot[i];
      int b = p >> 23;
      bin[(size_t)b * SLAB + gbase[b] + (i - loff[b])] = p;
    }
  }
}

// ---------------------------------------------------------------- sort S2: per-bucket node sort (128 nodes/bucket)
__global__ __launch_bounds__(256) void k_bsort(const unsigned* __restrict__ bin,
    const int* __restrict__ bkc, unsigned short* __restrict__ srcs,
    int* __restrict__ start, int* __restrict__ cntn) {
  __shared__ unsigned short outL[SLAB];
  __shared__ int hist[128], scA[128], cur[128];
  int tid = threadIdx.x;
  int b = blockIdx.x;
  size_t base = (size_t)b * SLAB;
  int cnt = bkc[b];
  int node0 = b << 7;
  int nnb = min(128, NN - node0);
  if (tid < 128) hist[tid] = 0;
  __syncthreads();
  for (int i = tid; i < cnt; i += 256)
    atomicAdd(&hist[(bin[base + i] >> 16) & 127], 1);
  __syncthreads();
  if (tid < 128) scA[tid] = hist[tid];
  __syncthreads();
  for (int off = 1; off < 128; off <<= 1) {
    int v = 0;
    if (tid < 128) v = scA[tid] + ((tid >= off) ? scA[tid - off] : 0);
    __syncthreads();
    if (tid < 128) scA[tid] = v;
    __syncthreads();
  }
  if (tid < 128) {
    int ex = scA[tid] - hist[tid];
    cur[tid] = ex;
    if (tid < nnb) { start[node0 + tid] = (int)base + ex; cntn[node0 + tid] = hist[tid]; }
  }
  __syncthreads();
  for (int i = tid; i < cnt; i += 256) {
    unsigned p = bin[base + i];
    int r = atomicAdd(&cur[(p >> 16) & 127], 1);
    outL[r] = (unsigned short)(p & 0xFFFFu);
  }
  __syncthreads();
  for (int i = tid; i < cnt; i += 256) srcs[base + i] = outL[i];
}

// ---------------------------------------------------------------- edge softmax + aggregate + ELU -> bf16 context
// one wave per node; fast path cnt<=64: pre-normalized ev, no conditionals in PV loop
__global__ __launch_bounds__(256) void k_agg(const unsigned char* __restrict__ hvb,
    const float* __restrict__ ld, const float* __restrict__ ls,
    const float* __restrict__ be_p, const int* __restrict__ start,
    const int* __restrict__ cntn, const unsigned short* __restrict__ srcs,
    unsigned short* __restrict__ ctxb) {
  int wid = (blockIdx.x * 256 + threadIdx.x) >> 6;
  int lane = threadIdx.x & 63;
  if (wid >= NN) return;
  int cnt = cntn[wid];
  int l8 = lane & 7, e8 = lane >> 3;
  floatx2 acc2[8];
  #pragma unroll
  for (int i = 0; i < 8; ++i) acc2[i] = (floatx2){0.f, 0.f};
  float rfin = 1.f;
  if (cnt > 0) {
    int s = start[wid];
    float base = ld[wid] + be_p[0];
    if (cnt <= 64) {
      float lg = -INFINITY;
      unsigned adr = 0;
      if (lane < cnt) {
        int sv = srcs[s + lane];
        adr = (unsigned)sv << 7;
        float l = base + ls[sv];
        lg = (l >= 0.f) ? l : 0.01f * l;
      }
      float mx = lg;
      #pragma unroll
      for (int o = 32; o; o >>= 1) mx = fmaxf(mx, __shfl_xor(mx, o));
      float ev = (lane < cnt) ? __expf(lg - mx) : 0.f;
      float dsum = ev;
      #pragma unroll
      for (int o = 32; o; o >>= 1) dsum += __shfl_xor(dsum, o);
      ev *= 1.f / dsum;                              // pre-normalize: no post-divide
      int nit = (cnt + 7) >> 3;
      #pragma unroll 2
      for (int j8 = 0; j8 < nit; ++j8) {
        int jj = (j8 << 3) + e8;
        float evj = __shfl(ev, jj);
        unsigned aj = (unsigned)__shfl((int)adr, jj);
        uint4 U = *(const uint4*)(hvb + aj + l8 * 16);
        floatx2 ev2 = (floatx2){evj, evj};
        acc2[0] += ev2 * __builtin_amdgcn_cvt_pk_f32_fp8((int)U.x, false);
        acc2[1] += ev2 * __builtin_amdgcn_cvt_pk_f32_fp8((int)U.x, true);
        acc2[2] += ev2 * __builtin_amdgcn_cvt_pk_f32_fp8((int)U.y, false);
        acc2[3] += ev2 * __builtin_amdgcn_cvt_pk_f32_fp8((int)U.y, true);
        acc2[4] += ev2 * __builtin_amdgcn_cvt_pk_f32_fp8((int)U.z, false);
        acc2[5] += ev2 * __builtin_amdgcn_cvt_pk_f32_fp8((int)U.z, true);
        acc2[6] += ev2 * __builtin_amdgcn_cvt_pk_f32_fp8((int)U.w, false);
        acc2[7] += ev2 * __builtin_amdgcn_cvt_pk_f32_fp8((int)U.w, true);
      }
    } else {
      // fallback: online softmax (cnt > 64; statistically ~never at this size)
      float m = -INFINITY, dsum = 0.f;
      for (int c0 = 0; c0 < cnt; c0 += 64) {
        int len = min(64, cnt - c0);
        float lg = -INFINITY;
        unsigned adr = 0;
        if (lane < len) {
          int sv = srcs[s + c0 + lane];
          adr = (unsigned)sv << 7;
          float l = base + ls[sv];
          lg = (l >= 0.f) ? l : 0.01f * l;
        }
        float cm = lg;
        #pragma unroll
        for (int o = 32; o; o >>= 1) cm = fmaxf(cm, __shfl_xor(cm, o));
        float nm = fmaxf(m, cm);
        float sc = __expf(m - nm);
        floatx2 sc2 = (floatx2){sc, sc};
        #pragma unroll
        for (int i = 0; i < 8; ++i) acc2[i] *= sc2;
        dsum *= sc;
        float ev = (lane < len) ? __expf(lg - nm) : 0.f;
        dsum += ev;
        int nit = (len + 7) >> 3;
        for (int j8 = 0; j8 < nit; ++j8) {
          int jj = (j8 << 3) + e8;
          float evj = __shfl(ev, jj);
          unsigned aj = (unsigned)__shfl((int)adr, jj);
          uint4 U = *(const uint4*)(hvb + aj + l8 * 16);
          floatx2 ev2 = (floatx2){evj, evj};
          acc2[0] += ev2 * __builtin_amdgcn_cvt_pk_f32_fp8((int)U.x, false);
          acc2[1] += ev2 * __builtin_amdgcn_cvt_pk_f32_fp8((int)U.x, true);
          acc2[2] += ev2 * __builtin_amdgcn_cvt_pk_f32_fp8((int)U.y, false);
          acc2[3] += ev2 * __builtin_amdgcn_cvt_pk_f32_fp8((int)U.y, true);
          acc2[4] += ev2 * __builtin_amdgcn_cvt_pk_f32_fp8((int)U.z, false);
          acc2[5] += ev2 * __builtin_amdgcn_cvt_pk_f32_fp8((int)U.z, true);
          acc2[6] += ev2 * __builtin_amdgcn_cvt_pk_f32_fp8((int)U.w, false);
          acc2[7] += ev2 * __builtin_amdgcn_cvt_pk_f32_fp8((int)U.w, true);
        }
        m = nm;
      }
      #pragma unroll
      for (int o = 32; o; o >>= 1) dsum += __shfl_xor(dsum, o);
      rfin = 1.f / dsum;
    }
  }
  #pragma unroll
  for (int o = 8; o <= 32; o <<= 1)
    #pragma unroll
    for (int i = 0; i < 8; ++i) {
      acc2[i].x += __shfl_xor(acc2[i].x, o);
      acc2[i].y += __shfl_xor(acc2[i].y, o);
    }
  if (lane < 32) {
    int g = lane & 7, p4 = lane >> 3;
    float v0 = acc2[p4 * 2].x * rfin, v1 = acc2[p4 * 2].y * rfin;
    float v2 = acc2[p4 * 2 + 1].x * rfin, v3 = acc2[p4 * 2 + 1].y * rfin;
    v0 = (v0 > 0.f) ? v0 : expm1f(v0);
    v1 = (v1 > 0.f) ? v1 : expm1f(v1);
    v2 = (v2 > 0.f) ? v2 : expm1f(v2);
    v3 = (v3 > 0.f) ? v3 : expm1f(v3);
    uint2 u;
    u.x = (unsigned)f2bf(v0) | ((unsigned)f2bf(v1) << 16);
    u.y = (unsigned)f2bf(v2) | ((unsigned)f2bf(v3) << 16);
    *(uint2*)(ctxb + (size_t)wid * 128 + g * 16 + p4 * 4) = u;
  }
}

// ---------------------------------------------------------------- fused MLP [MFMA], 32-row tiles, no global atomics
__global__ __launch_bounds__(256) void k_mlp2(const unsigned short* __restrict__ ctxb,
    const float* __restrict__ nf,
    const unsigned short* __restrict__ w1t, const float* __restrict__ b1,
    const unsigned short* __restrict__ w2t, const float* __restrict__ b2,
    float* __restrict__ out, float* __restrict__ pbn, float* __restrict__ pbq) {
  __shared__ unsigned short xs[MROWS][264];          // [m][k] bf16 (ctx | nf)
  __shared__ unsigned short h1s[MROWS][136];         // [m][n] bf16
  __shared__ float bns[128], bnq[128];
  int tid = threadIdx.x;
  int m0 = blockIdx.x * MROWS;
  if (tid < 128) { bns[tid] = 0.f; bnq[tid] = 0.f; }
  #pragma unroll
  for (int e = 0; e < 2; ++e) {
    int idx = tid + 256 * e;
    int row = idx >> 4, c8 = idx & 15;
    int m = m0 + row; if (m >= NN) m = NN - 1;
    uint4 v = *(const uint4*)(ctxb + (size_t)m * 128 + c8 * 8);
    *(uint4*)&xs[row][c8 * 8] = v;
  }
  #pragma unroll
  for (int e = 0; e < 4; ++e) {
    int idx = tid + 256 * e;
    int row = idx >> 5, c4 = idx & 31;
    int m = m0 + row; if (m >= NN) m = NN - 1;
    float4 w = *(const float4*)(nf + (size_t)m * 128 + c4 * 4);
    ushort4 cc;
    cc.x = f2bf(w.x); cc.y = f2bf(w.y); cc.z = f2bf(w.z); cc.w = f2bf(w.w);
    *(ushort4*)&xs[row][128 + c4 * 4] = cc;
  }
  __syncthreads();
  int wid = tid >> 6, lane = tid & 63;
  int wm = wid >> 1, wn = wid & 1;                   // wave tile: 16 rows x 64 cols
  int l15 = lane & 15, lg = lane >> 4;
  f32x4 acc[4];
  #pragma unroll
  for (int nf2 = 0; nf2 < 4; ++nf2) acc[nf2] = (f32x4){0.f, 0.f, 0.f, 0.f};
  for (int ks = 0; ks < 8; ++ks) {
    short8v a = *(const short8v*)&xs[wm * 16 + l15][ks * 32 + lg * 8];
    #pragma unroll
    for (int nf2 = 0; nf2 < 4; ++nf2) {
      int n = wn * 64 + nf2 * 16 + l15;
      short8v b = *(const short8v*)(w1t + (size_t)n * 256 + ks * 32 + lg * 8);
      acc[nf2] = __builtin_amdgcn_mfma_f32_16x16x32_bf16(a, b, acc[nf2], 0, 0, 0);
    }
  }
  {
    float b1n[4];
    #pragma unroll
    for (int nf2 = 0; nf2 < 4; ++nf2) b1n[nf2] = b1[wn * 64 + nf2 * 16 + l15];
    #pragma unroll
    for (int nf2 = 0; nf2 < 4; ++nf2)
      #pragma unroll
      for (int r = 0; r < 4; ++r) {
        int row = wm * 16 + lg * 4 + r;
        int col = wn * 64 + nf2 * 16 + l15;
        h1s[row][col] = f2bf(fmaxf(acc[nf2][r] + b1n[nf2], 0.f));
      }
  }
  __syncthreads();
  f32x4 acc2[4];
  #pragma unroll
  for (int nf2 = 0; nf2 < 4; ++nf2) acc2[nf2] = (f32x4){0.f, 0.f, 0.f, 0.f};
  for (int ks = 0; ks < 4; ++ks) {
    short8v bh = *(const short8v*)&h1s[wm * 16 + l15][ks * 32 + lg * 8];
    #pragma unroll
    for (int nf2 = 0; nf2 < 4; ++nf2) {
      int n = wn * 64 + nf2 * 16 + l15;
      short8v aw = *(const short8v*)(w2t + (size_t)n * 128 + ks * 32 + lg * 8);
      acc2[nf2] = __builtin_amdgcn_mfma_f32_16x16x32_bf16(aw, bh, acc2[nf2], 0, 0, 0);
    }
  }
  {
    int m = m0 + wm * 16 + l15;
    bool valid = (m < NN);
    float hs[4][4], hq[4][4];
    #pragma unroll
    for (int nf2 = 0; nf2 < 4; ++nf2) {
      int f0 = wn * 64 + nf2 * 16 + lg * 4;
      float4 b24 = *(const float4*)(b2 + f0);
      float h0 = fmaxf(acc2[nf2][0] + b24.x, 0.f);
      float h1v = fmaxf(acc2[nf2][1] + b24.y, 0.f);
      float h2v = fmaxf(acc2[nf2][2] + b24.z, 0.f);
      float h3v = fmaxf(acc2[nf2][3] + b24.w, 0.f);
      if (valid) {
        float4 o = make_float4(h0, h1v, h2v, h3v);
        *(float4*)(out + (size_t)m * 128 + f0) = o;
      } else { h0 = h1v = h2v = h3v = 0.f; }
      hs[nf2][0] = h0; hs[nf2][1] = h1v; hs[nf2][2] = h2v; hs[nf2][3] = h3v;
      hq[nf2][0] = h0 * h0; hq[nf2][1] = h1v * h1v;
      hq[nf2][2] = h2v * h2v; hq[nf2][3] = h3v * h3v;
    }
    #pragma unroll
    for (int o = 1; o <= 8; o <<= 1)
      #pragma unroll
      for (int nf2 = 0; nf2 < 4; ++nf2)
        #pragma unroll
        for (int r = 0; r < 4; ++r) {
          hs[nf2][r] += __shfl_xor(hs[nf2][r], o);
          hq[nf2][r] += __shfl_xor(hq[nf2][r], o);
        }
    if (l15 == 0) {
      #pragma unroll
      for (int nf2 = 0; nf2 < 4; ++nf2) {
        int f0 = wn * 64 + nf2 * 16 + lg * 4;
        #pragma unroll
        for (int r = 0; r < 4; ++r) {
          atomicAdd(&bns[f0 + r], hs[nf2][r]);
          atomicAdd(&bnq[f0 + r], hq[nf2][r]);
        }
      }
    }
  }
  __syncthreads();
  if (tid < 128) {
    pbn[(size_t)blockIdx.x * 128 + tid] = bns[tid];
    pbq[(size_t)blockIdx.x * 128 + tid] = bnq[tid];
  }
}

// ---------------------------------------------------------------- BN stats: reduce per-block partials (one block per feature)
__global__ __launch_bounds__(256) void k_bnstats2(const float* __restrict__ pbn,
    const float* __restrict__ pbq, float* __restrict__ mean,
    float* __restrict__ istd) {
  int f = blockIdx.x;
  float s = 0.f, q = 0.f;
  for (int b = threadIdx.x; b < MGRID; b += 256) {
    s += pbn[(size_t)b * 128 + f];
    q += pbq[(size_t)b * 128 + f];
  }
  #pragma unroll
  for (int o = 32; o; o >>= 1) { s += __shfl_xor(s, o); q += __shfl_xor(q, o); }
  __shared__ float ss[4], sq[4];
  int wid = threadIdx.x >> 6, lane = threadIdx.x & 63;
  if (lane == 0) { ss[wid] = s; sq[wid] = q; }
  __syncthreads();
  if (threadIdx.x == 0) {
    float S = ss[0] + ss[1] + ss[2] + ss[3];
    float Q = sq[0] + sq[1] + sq[2] + sq[3];
    float mu = S / (float)NN;
    float var = fmaxf(Q / (float)NN - mu * mu, 0.f);
    mean[f] = mu;
    istd[f] = 1.f / sqrtf(var + 1e-5f);
  }
}

__global__ __launch_bounds__(256) void k_bnorm(float* __restrict__ out,
    const float* __restrict__ mean, const float* __restrict__ istd,
    const float* __restrict__ gamma, const float* __restrict__ beta) {
  int idx = blockIdx.x * 256 + threadIdx.x;
  float4* p = (float4*)out;
  float4 v = p[idx];
  int f = (idx & 31) << 2;
  v.x = gamma[f + 0] * (v.x - mean[f + 0]) * istd[f + 0] + beta[f + 0];
  v.y = gamma[f + 1] * (v.y - mean[f + 1]) * istd[f + 1] + beta[f + 1];
  v.z = gamma[f + 2] * (v.z - mean[f + 2]) * istd[f + 2] + beta[f + 2];
  v.w = gamma[f + 3] * (v.w - mean[f + 3]) * istd[f + 3] + beta[f + 3];
  p[idx] = v;
}

// ----------------------------------------------------------------
extern "C" void kernel_launch(void* const* d_in, const int* in_sizes, int n_in,
                              void* d_out, int out_size, void* d_ws, size_t ws_size,
                              hipStream_t stream) {
  (void)in_sizes; (void)n_in; (void)out_size; (void)ws_size;
  const float* nf    = (const float*)d_in[0];
  const int*   src   = (const int*)d_in[1];
  const int*   dst   = (const int*)d_in[2];
  const float* wed   = (const float*)d_in[3];
  const float* wes   = (const float*)d_in[4];
  const float* be    = (const float*)d_in[5];
  const float* wp    = (const float*)d_in[6];
  const float* bp    = (const float*)d_in[7];
  const float* w1    = (const float*)d_in[8];
  const float* b1    = (const float*)d_in[9];
  const float* w2    = (const float*)d_in[10];
  const float* b2    = (const float*)d_in[11];
  const float* gamma = (const float*)d_in[12];
  const float* beta  = (const float*)d_in[13];
  float* out = (float*)d_out;
  char* ws = (char*)d_ws;

  unsigned char*  hvb  = (unsigned char*)(ws + HVB_OFF);
  unsigned short* ctxb = (unsigned short*)(ws + CTXB_OFF);
  unsigned*       bin  = (unsigned*)(ws + BIN_OFF);
  unsigned short* srcs = (unsigned short*)(ws + SRCS_OFF);
  float* ld    = (float*)(ws + LD_OFF);
  float* ls    = (float*)(ws + LS_OFF);
  int*   start = (int*)(ws + START_OFF);
  int*   cntn  = (int*)(ws + CNTN_OFF);
  unsigned short* w1t = (unsigned short*)(ws + W1T_OFF);
  unsigned short* w2t = (unsigned short*)(ws + W2T_OFF);
  unsigned short* wpt = (unsigned short*)(ws + WPT_OFF);
  int*   bkc   = (int*)(ws + BKC_OFF);
  float* mean  = (float*)(ws + MEAN_OFF);
  float* istd  = (float*)(ws + ISTD_OFF);
  float* pbn   = (float*)(ws + PBN_OFF);
  float* pbq   = (float*)(ws + PBQ_OFF);

  hipMemsetAsync(ws + ZERO_OFF, 0, ZERO_LEN, stream);

  k_prep_w<<<256, 256, 0, stream>>>(w1, w2, wp, w1t, w2t, wpt);
  k_bin<<<196, 256, 0, stream>>>(src, dst, bkc, bin);
  k_hv2<<<(NN + 63) / 64, 256, 0, stream>>>(nf, wpt, bp, wed, wes, ld, ls, hvb);
  k_bsort<<<NB, 256, 0, stream>>>(bin, bkc, srcs, start, cntn);
  k_agg<<<12500, 256, 0, stream>>>(hvb, ld, ls, be, start, cntn, srcs, ctxb);
  k_mlp2<<<MGRID, 256, 0, stream>>>(ctxb, nf, w1t, b1, w2t, b2, out, pbn, pbq);
  k_bnstats2<<<128, 256, 0, stream>>>(pbn, pbq, mean, istd);
  k_bnorm<<<(NN * DD / 4) / 256, 256, 0, stream>>>(out, mean, istd, gamma, beta);
}